// Round 1
// baseline (25646.793 us; speedup 1.0000x reference)
//
#include <hip/hip_runtime.h>
#include <hip/hip_bf16.h>
#include <math.h>

// Problem constants (ViT): B=8, C=3, H=384, P=16 -> 24x24=576 patches, S=577
#define BB 8
#define CC 3
#define HH 384
#define PP 16
#define HP 24            // H/P
#define NP 576           // patches per image
#define PD 768           // patch dim = C*P*P
#define DIM 768
#define DEPTH 8
#define HEADS 12
#define DH 64            // DIM/HEADS
#define MLP 3072
#define SS 577           // seq len = NP+1
#define BS (BB*SS)       // 4616 rows
#define LN_EPS 1e-5f

// ---------------------------------------------------------------------------
// Patchify: img (B,C,H,H) -> Xp (B*NP, PD) with vec index (p1*P+p2)*C + c
// ---------------------------------------------------------------------------
__global__ __launch_bounds__(256) void patchify_k(const float* __restrict__ img,
                                                  float* __restrict__ xp) {
    int idx = blockIdx.x * 256 + threadIdx.x;
    const int total = BB * NP * PD;
    if (idx >= total) return;
    int b = idx / (NP * PD);
    int r = idx % (NP * PD);
    int n = r / PD;
    int j = r % PD;
    int c  = j % CC;
    int t  = j / CC;
    int p2 = t % PP;
    int p1 = t / PP;
    int hh = n / HP;
    int ww = n % HP;
    int row = hh * PP + p1;
    int col = ww * PP + p2;
    xp[idx] = img[(((size_t)b * CC + c) * HH + row) * HH + col];
}

// ---------------------------------------------------------------------------
// Build residual stream x (B,S,DIM): row0 = cls + pos[0], rows 1.. = pe + pos
// ---------------------------------------------------------------------------
__global__ __launch_bounds__(256) void build_x_k(const float* __restrict__ pe,   // (B*NP, DIM), bias applied
                                                 const float* __restrict__ cls,  // (DIM)
                                                 const float* __restrict__ pos,  // (S, DIM)
                                                 float* __restrict__ x) {
    int idx = blockIdx.x * 256 + threadIdx.x;
    const int total = BB * SS * DIM;
    if (idx >= total) return;
    int b = idx / (SS * DIM);
    int r = idx % (SS * DIM);
    int i = r / DIM;
    int d = r % DIM;
    float p = pos[i * DIM + d];
    float v = (i == 0) ? cls[d] : pe[((size_t)b * NP + (i - 1)) * DIM + d];
    x[idx] = v + p;
}

// ---------------------------------------------------------------------------
// LayerNorm: one block per row (768 cols, 256 threads x 3 elems)
// ---------------------------------------------------------------------------
__global__ __launch_bounds__(256) void ln_k(const float* __restrict__ x,
                                            const float* __restrict__ g,
                                            const float* __restrict__ bt,
                                            float* __restrict__ y) {
    __shared__ float sm[8];
    int row = blockIdx.x, tid = threadIdx.x;
    const float* xr = x + (size_t)row * DIM;
    float v0 = xr[tid], v1 = xr[tid + 256], v2 = xr[tid + 512];
    float s = v0 + v1 + v2;
    for (int o = 32; o; o >>= 1) s += __shfl_xor(s, o);
    if ((tid & 63) == 0) sm[tid >> 6] = s;
    __syncthreads();
    float mean = (sm[0] + sm[1] + sm[2] + sm[3]) * (1.f / 768.f);
    float q0 = v0 - mean, q1 = v1 - mean, q2 = v2 - mean;
    float s2 = q0 * q0 + q1 * q1 + q2 * q2;
    for (int o = 32; o; o >>= 1) s2 += __shfl_xor(s2, o);
    if ((tid & 63) == 0) sm[4 + (tid >> 6)] = s2;
    __syncthreads();
    float var = (sm[4] + sm[5] + sm[6] + sm[7]) * (1.f / 768.f);
    float rstd = rsqrtf(var + LN_EPS);
    float* yr = y + (size_t)row * DIM;
    yr[tid]       = q0 * rstd * g[tid]       + bt[tid];
    yr[tid + 256] = q1 * rstd * g[tid + 256] + bt[tid + 256];
    yr[tid + 512] = q2 * rstd * g[tid + 512] + bt[tid + 512];
}

// ---------------------------------------------------------------------------
// Tiled fp32 GEMM: C = epilogue(A @ B + bias)
//   A: (M,K) row-major, B: (K,N) row-major, N % 64 == 0, K % 16 == 0.
//   OP 0: out = acc + bias
//   OP 1: out = gelu(acc + bias)          (exact erf gelu)
//   OP 2: out = out + acc + bias          (residual accumulate)
// 64x64 block tile, 256 threads, 4x4 register micro-tile, BK=16.
// ---------------------------------------------------------------------------
template <int OP>
__global__ __launch_bounds__(256) void gemm_k(const float* __restrict__ A,
                                              const float* __restrict__ Bm,
                                              const float* __restrict__ bias,
                                              float* __restrict__ Cm,
                                              int M, int N, int K) {
    __shared__ float As[16][64];
    __shared__ float Bs[16][64];
    int tid = threadIdx.x;
    int tx = tid & 15, ty = tid >> 4;
    int m0 = blockIdx.y * 64, n0 = blockIdx.x * 64;

    // load mapping
    int la_m = tid >> 2;          // 0..63
    int la_k = (tid & 3) << 2;    // 0,4,8,12
    int lb_k = tid >> 4;          // 0..15
    int lb_n = (tid & 15) << 2;   // 0..60

    float acc[4][4];
#pragma unroll
    for (int i = 0; i < 4; ++i)
#pragma unroll
        for (int j = 0; j < 4; ++j) acc[i][j] = 0.f;

    for (int k0 = 0; k0 < K; k0 += 16) {
        float4 av;
        if (m0 + la_m < M)
            av = *reinterpret_cast<const float4*>(A + (size_t)(m0 + la_m) * K + k0 + la_k);
        else
            av = make_float4(0.f, 0.f, 0.f, 0.f);
        As[la_k + 0][la_m] = av.x;
        As[la_k + 1][la_m] = av.y;
        As[la_k + 2][la_m] = av.z;
        As[la_k + 3][la_m] = av.w;
        float4 bv = *reinterpret_cast<const float4*>(Bm + (size_t)(k0 + lb_k) * N + n0 + lb_n);
        *reinterpret_cast<float4*>(&Bs[lb_k][lb_n]) = bv;
        __syncthreads();
#pragma unroll
        for (int kk = 0; kk < 16; ++kk) {
            float4 a4 = *reinterpret_cast<const float4*>(&As[kk][ty << 2]);
            float4 b4 = *reinterpret_cast<const float4*>(&Bs[kk][tx << 2]);
            float av_[4] = {a4.x, a4.y, a4.z, a4.w};
            float bv_[4] = {b4.x, b4.y, b4.z, b4.w};
#pragma unroll
            for (int i = 0; i < 4; ++i)
#pragma unroll
                for (int j = 0; j < 4; ++j) acc[i][j] += av_[i] * bv_[j];
        }
        __syncthreads();
    }

#pragma unroll
    for (int i = 0; i < 4; ++i) {
        int m = m0 + (ty << 2) + i;
        if (m >= M) continue;
#pragma unroll
        for (int j = 0; j < 4; ++j) {
            int n = n0 + (tx << 2) + j;
            float v = acc[i][j] + (bias ? bias[n] : 0.f);
            if (OP == 1) {
                v = 0.5f * v * (1.f + erff(v * 0.70710678118654752f));
            }
            size_t ci = (size_t)m * N + n;
            if (OP == 2) v += Cm[ci];
            Cm[ci] = v;
        }
    }
}

// ---------------------------------------------------------------------------
// Attention: one wave (64 lanes) per (b, h, query i). Online softmax, no
// score matrix. qkv: (B, S, 3*DIM); out o: (B, S, DIM). No 1/sqrt(d) scale
// (faithful to reference).
// ---------------------------------------------------------------------------
__global__ __launch_bounds__(256) void attn_k(const float* __restrict__ qkv,
                                              float* __restrict__ o) {
    int wave = threadIdx.x >> 6;
    int lane = threadIdx.x & 63;
    int row = blockIdx.x * 4 + wave;          // 0 .. B*HEADS*S-1
    const int total = BB * HEADS * SS;
    if (row >= total) return;
    int b = row / (HEADS * SS);
    int r = row % (HEADS * SS);
    int h = r / SS;
    int i = r % SS;

    const size_t stride = 3 * DIM;
    const float* qp = qkv + ((size_t)b * SS + i) * stride + h * DH;
    const float* kbase = qkv + (size_t)b * SS * stride + DIM + h * DH + lane;
    const float* vbase = qkv + (size_t)b * SS * stride + 2 * DIM + h * DH + lane;

    float qv = qp[lane];
    float m = -INFINITY, l = 0.f, acc = 0.f;
    for (int j = 0; j < SS; ++j) {
        float kv = kbase[(size_t)j * stride];
        float vv = vbase[(size_t)j * stride];
        float dot = qv * kv;
        for (int off = 32; off; off >>= 1) dot += __shfl_xor(dot, off);
        float mn = fmaxf(m, dot);
        float alpha = __expf(m - mn);    // first iter: exp(-inf) = 0
        float p = __expf(dot - mn);
        l = l * alpha + p;
        acc = acc * alpha + p * vv;
        m = mn;
    }
    o[((size_t)b * SS + i) * DIM + h * DH + lane] = acc / l;
}

// ---------------------------------------------------------------------------
// Output: x[:, 1:, :] -> out (B, NP, DIM)
// ---------------------------------------------------------------------------
__global__ __launch_bounds__(256) void copy_out_k(const float* __restrict__ x,
                                                  float* __restrict__ out) {
    int idx = blockIdx.x * 256 + threadIdx.x;
    const int total = BB * NP * DIM;
    if (idx >= total) return;
    int b = idx / (NP * DIM);
    int r = idx % (NP * DIM);
    int n = r / DIM;
    int d = r % DIM;
    out[idx] = x[((size_t)b * SS + 1 + n) * DIM + d];
}

// ---------------------------------------------------------------------------
extern "C" void kernel_launch(void* const* d_in, const int* in_sizes, int n_in,
                              void* d_out, int out_size, void* d_ws, size_t ws_size,
                              hipStream_t stream) {
    const float* img     = (const float*)d_in[0];
    const float* pos     = (const float*)d_in[1];
    const float* cls     = (const float*)d_in[2];
    const float* patch_w = (const float*)d_in[3];
    const float* patch_b = (const float*)d_in[4];
    const float* ln1_g   = (const float*)d_in[5];
    const float* ln1_b   = (const float*)d_in[6];
    const float* qkv_w   = (const float*)d_in[7];
    const float* out_w   = (const float*)d_in[8];
    const float* out_b   = (const float*)d_in[9];
    const float* ln2_g   = (const float*)d_in[10];
    const float* ln2_b   = (const float*)d_in[11];
    const float* ff1_w   = (const float*)d_in[12];
    const float* ff1_b   = (const float*)d_in[13];
    const float* ff2_w   = (const float*)d_in[14];
    const float* ff2_b   = (const float*)d_in[15];
    float* out = (float*)d_out;

    // workspace layout (floats): x | y | t1 | big
    float* ws = (float*)d_ws;
    float* x   = ws;
    float* y   = x + (size_t)BS * DIM;
    float* t1  = y + (size_t)BS * DIM;
    float* big = t1 + (size_t)BS * DIM;   // BS * MLP floats

    const int threads = 256;
    // 1. patchify into big
    {
        int tot = BB * NP * PD;
        patchify_k<<<(tot + 255) / 256, threads, 0, stream>>>(img, big);
    }
    // 2. patch embed: t1 = Xp @ patch_w + patch_b   (M=4608, N=768, K=768)
    gemm_k<0><<<dim3(DIM / 64, (BB * NP) / 64), threads, 0, stream>>>(
        big, patch_w, patch_b, t1, BB * NP, DIM, PD);
    // 3. assemble x with cls token + positional embedding
    {
        int tot = BB * SS * DIM;
        build_x_k<<<(tot + 255) / 256, threads, 0, stream>>>(t1, cls, pos, x);
    }

    const int mblk = (BS + 63) / 64;   // 73
    for (int l = 0; l < DEPTH; ++l) {
        // ln1
        ln_k<<<BS, threads, 0, stream>>>(x, ln1_g + l * DIM, ln1_b + l * DIM, y);
        // qkv = y @ wqkv  (no bias)   M=4616, N=2304, K=768
        gemm_k<0><<<dim3((3 * DIM) / 64, mblk), threads, 0, stream>>>(
            y, qkv_w + (size_t)l * DIM * 3 * DIM, nullptr, big, BS, 3 * DIM, DIM);
        // attention -> t1
        {
            int rows = BB * HEADS * SS;
            attn_k<<<(rows + 3) / 4, threads, 0, stream>>>(big, t1);
        }
        // x += t1 @ out_w + out_b
        gemm_k<2><<<dim3(DIM / 64, mblk), threads, 0, stream>>>(
            t1, out_w + (size_t)l * DIM * DIM, out_b + l * DIM, x, BS, DIM, DIM);
        // ln2
        ln_k<<<BS, threads, 0, stream>>>(x, ln2_g + l * DIM, ln2_b + l * DIM, y);
        // big = gelu(y @ w1 + b1)   M=4616, N=3072, K=768
        gemm_k<1><<<dim3(MLP / 64, mblk), threads, 0, stream>>>(
            y, ff1_w + (size_t)l * DIM * MLP, ff1_b + l * MLP, big, BS, MLP, DIM);
        // x += big @ w2 + b2   M=4616, N=768, K=3072
        gemm_k<2><<<dim3(DIM / 64, mblk), threads, 0, stream>>>(
            big, ff2_w + (size_t)l * MLP * DIM, ff2_b + l * DIM, x, BS, DIM, MLP);
    }

    // output: drop cls row
    {
        int tot = BB * NP * DIM;
        copy_out_k<<<(tot + 255) / 256, threads, 0, stream>>>(x, out);
    }
}

// Round 2
// 9601.857 us; speedup vs baseline: 2.6710x; 2.6710x over previous
//
#include <hip/hip_runtime.h>
#include <hip/hip_bf16.h>
#include <math.h>

// Problem constants (ViT): B=8, C=3, H=384, P=16 -> 24x24=576 patches, S=577
#define BB 8
#define CC 3
#define HH 384
#define PP 16
#define HP 24            // H/P
#define NP 576           // patches per image
#define PD 768           // patch dim = C*P*P
#define DIM 768
#define DEPTH 8
#define HEADS 12
#define DH 64            // DIM/HEADS
#define MLP 3072
#define SS 577           // seq len = NP+1
#define BS (BB*SS)       // 4616 rows
#define LN_EPS 1e-5f
#define NKT 10           // ceil(577/64) key tiles

// ---------------------------------------------------------------------------
// Patchify: img (B,C,H,H) -> Xp (B*NP, PD) with vec index (p1*P+p2)*C + c
// ---------------------------------------------------------------------------
__global__ __launch_bounds__(256) void patchify_k(const float* __restrict__ img,
                                                  float* __restrict__ xp) {
    int idx = blockIdx.x * 256 + threadIdx.x;
    const int total = BB * NP * PD;
    if (idx >= total) return;
    int b = idx / (NP * PD);
    int r = idx % (NP * PD);
    int n = r / PD;
    int j = r % PD;
    int c  = j % CC;
    int t  = j / CC;
    int p2 = t % PP;
    int p1 = t / PP;
    int hh = n / HP;
    int ww = n % HP;
    int row = hh * PP + p1;
    int col = ww * PP + p2;
    xp[idx] = img[(((size_t)b * CC + c) * HH + row) * HH + col];
}

// ---------------------------------------------------------------------------
// Build residual stream x (B,S,DIM): row0 = cls + pos[0], rows 1.. = pe + pos
// ---------------------------------------------------------------------------
__global__ __launch_bounds__(256) void build_x_k(const float* __restrict__ pe,
                                                 const float* __restrict__ cls,
                                                 const float* __restrict__ pos,
                                                 float* __restrict__ x) {
    int idx = blockIdx.x * 256 + threadIdx.x;
    const int total = BB * SS * DIM;
    if (idx >= total) return;
    int b = idx / (SS * DIM);
    int r = idx % (SS * DIM);
    int i = r / DIM;
    int d = r % DIM;
    float p = pos[i * DIM + d];
    float v = (i == 0) ? cls[d] : pe[((size_t)b * NP + (i - 1)) * DIM + d];
    x[idx] = v + p;
}

// ---------------------------------------------------------------------------
// LayerNorm: one block per row (768 cols, 256 threads x 3 elems)
// ---------------------------------------------------------------------------
__global__ __launch_bounds__(256) void ln_k(const float* __restrict__ x,
                                            const float* __restrict__ g,
                                            const float* __restrict__ bt,
                                            float* __restrict__ y) {
    __shared__ float sm[8];
    int row = blockIdx.x, tid = threadIdx.x;
    const float* xr = x + (size_t)row * DIM;
    float v0 = xr[tid], v1 = xr[tid + 256], v2 = xr[tid + 512];
    float s = v0 + v1 + v2;
    for (int o = 32; o; o >>= 1) s += __shfl_xor(s, o);
    if ((tid & 63) == 0) sm[tid >> 6] = s;
    __syncthreads();
    float mean = (sm[0] + sm[1] + sm[2] + sm[3]) * (1.f / 768.f);
    float q0 = v0 - mean, q1 = v1 - mean, q2 = v2 - mean;
    float s2 = q0 * q0 + q1 * q1 + q2 * q2;
    for (int o = 32; o; o >>= 1) s2 += __shfl_xor(s2, o);
    if ((tid & 63) == 0) sm[4 + (tid >> 6)] = s2;
    __syncthreads();
    float var = (sm[4] + sm[5] + sm[6] + sm[7]) * (1.f / 768.f);
    float rstd = rsqrtf(var + LN_EPS);
    float* yr = y + (size_t)row * DIM;
    yr[tid]       = q0 * rstd * g[tid]       + bt[tid];
    yr[tid + 256] = q1 * rstd * g[tid + 256] + bt[tid + 256];
    yr[tid + 512] = q2 * rstd * g[tid + 512] + bt[tid + 512];
}

// ---------------------------------------------------------------------------
// Tiled fp32 GEMM: C = epilogue(A @ B + bias)
//   OP 0: out = acc + bias
//   OP 1: out = gelu(acc + bias)          (exact erf gelu)
//   OP 2: out = out + acc + bias          (residual accumulate)
// 64x64 block tile, 256 threads, 4x4 register micro-tile, BK=16.
// ---------------------------------------------------------------------------
template <int OP>
__global__ __launch_bounds__(256) void gemm_k(const float* __restrict__ A,
                                              const float* __restrict__ Bm,
                                              const float* __restrict__ bias,
                                              float* __restrict__ Cm,
                                              int M, int N, int K) {
    __shared__ float As[16][64];
    __shared__ float Bs[16][64];
    int tid = threadIdx.x;
    int tx = tid & 15, ty = tid >> 4;
    int m0 = blockIdx.y * 64, n0 = blockIdx.x * 64;

    int la_m = tid >> 2;          // 0..63
    int la_k = (tid & 3) << 2;    // 0,4,8,12
    int lb_k = tid >> 4;          // 0..15
    int lb_n = (tid & 15) << 2;   // 0..60

    float acc[4][4];
#pragma unroll
    for (int i = 0; i < 4; ++i)
#pragma unroll
        for (int j = 0; j < 4; ++j) acc[i][j] = 0.f;

    for (int k0 = 0; k0 < K; k0 += 16) {
        float4 av;
        if (m0 + la_m < M)
            av = *reinterpret_cast<const float4*>(A + (size_t)(m0 + la_m) * K + k0 + la_k);
        else
            av = make_float4(0.f, 0.f, 0.f, 0.f);
        As[la_k + 0][la_m] = av.x;
        As[la_k + 1][la_m] = av.y;
        As[la_k + 2][la_m] = av.z;
        As[la_k + 3][la_m] = av.w;
        float4 bv = *reinterpret_cast<const float4*>(Bm + (size_t)(k0 + lb_k) * N + n0 + lb_n);
        *reinterpret_cast<float4*>(&Bs[lb_k][lb_n]) = bv;
        __syncthreads();
#pragma unroll
        for (int kk = 0; kk < 16; ++kk) {
            float4 a4 = *reinterpret_cast<const float4*>(&As[kk][ty << 2]);
            float4 b4 = *reinterpret_cast<const float4*>(&Bs[kk][tx << 2]);
            float av_[4] = {a4.x, a4.y, a4.z, a4.w};
            float bv_[4] = {b4.x, b4.y, b4.z, b4.w};
#pragma unroll
            for (int i = 0; i < 4; ++i)
#pragma unroll
                for (int j = 0; j < 4; ++j) acc[i][j] += av_[i] * bv_[j];
        }
        __syncthreads();
    }

#pragma unroll
    for (int i = 0; i < 4; ++i) {
        int m = m0 + (ty << 2) + i;
        if (m >= M) continue;
#pragma unroll
        for (int j = 0; j < 4; ++j) {
            int n = n0 + (tx << 2) + j;
            float v = acc[i][j] + (bias ? bias[n] : 0.f);
            if (OP == 1) {
                v = 0.5f * v * (1.f + erff(v * 0.70710678118654752f));
            }
            size_t ci = (size_t)m * N + n;
            if (OP == 2) v += Cm[ci];
            Cm[ci] = v;
        }
    }
}

// ---------------------------------------------------------------------------
// Flash-style attention, fp32. One block per (b*h, q-tile of 64).
// S = Q K^T (no 1/sqrt(d) scale -- faithful), online softmax, O += P V.
// Thread layout: tx = tid&15 (cols/4), ty = tid>>4 (rows/4); 4x4 microtile.
// LDS: Qs[d][q], Ks[d][k] (d-major for QK^T), Vs[k][d], Ps[q][k]. 64 KB.
// ---------------------------------------------------------------------------
__global__ __launch_bounds__(256) void fattn_k(const float* __restrict__ qkv,
                                               float* __restrict__ o) {
    __shared__ float Qs[64][64];   // [d][q]
    __shared__ float Ks[64][64];   // [d][k]
    __shared__ float Vs[64][64];   // [k][d]
    __shared__ float Ps[64][64];   // [q][k]

    int bh = blockIdx.x;
    int b = bh / HEADS, h = bh % HEADS;
    int q0 = blockIdx.y * 64;
    int tid = threadIdx.x;
    int tx = tid & 15, ty = tid >> 4;

    const size_t stride = 3 * DIM;
    const float* qbase = qkv + (size_t)b * SS * stride + h * DH;
    const float* kbase = qbase + DIM;
    const float* vbase = qbase + 2 * DIM;

    // stage Q tile transposed: Qs[d][q]
#pragma unroll
    for (int rr = 0; rr < 4; ++rr) {
        int r = rr * 16 + ty;           // local q 0..63
        int gq = q0 + r;
        float4 v;
        if (gq < SS) v = *reinterpret_cast<const float4*>(qbase + (size_t)gq * stride + tx * 4);
        else v = make_float4(0.f, 0.f, 0.f, 0.f);
        Qs[tx * 4 + 0][r] = v.x;
        Qs[tx * 4 + 1][r] = v.y;
        Qs[tx * 4 + 2][r] = v.z;
        Qs[tx * 4 + 3][r] = v.w;
    }

    float m[4], l[4], O[4][4];
#pragma unroll
    for (int i = 0; i < 4; ++i) {
        m[i] = -INFINITY; l[i] = 0.f;
#pragma unroll
        for (int j = 0; j < 4; ++j) O[i][j] = 0.f;
    }

    for (int t = 0; t < NKT; ++t) {
        int k0 = t * 64;
        __syncthreads();   // prior iteration done reading Ks/Vs/Ps
        // stage K tile (transposed) and V tile (natural)
#pragma unroll
        for (int rr = 0; rr < 4; ++rr) {
            int r = rr * 16 + ty;       // local k
            int gk = k0 + r;
            float4 kv, vv;
            if (gk < SS) {
                kv = *reinterpret_cast<const float4*>(kbase + (size_t)gk * stride + tx * 4);
                vv = *reinterpret_cast<const float4*>(vbase + (size_t)gk * stride + tx * 4);
            } else {
                kv = make_float4(0.f, 0.f, 0.f, 0.f);
                vv = make_float4(0.f, 0.f, 0.f, 0.f);
            }
            Ks[tx * 4 + 0][r] = kv.x;
            Ks[tx * 4 + 1][r] = kv.y;
            Ks[tx * 4 + 2][r] = kv.z;
            Ks[tx * 4 + 3][r] = kv.w;
            *reinterpret_cast<float4*>(&Vs[r][tx * 4]) = vv;
        }
        __syncthreads();

        // S fragment: rows = queries ty*4.., cols = keys tx*4..
        float s[4][4];
#pragma unroll
        for (int i = 0; i < 4; ++i)
#pragma unroll
            for (int j = 0; j < 4; ++j) s[i][j] = 0.f;
        for (int d = 0; d < 64; ++d) {
            float4 qa = *reinterpret_cast<const float4*>(&Qs[d][ty * 4]);
            float4 kb = *reinterpret_cast<const float4*>(&Ks[d][tx * 4]);
            float qa_[4] = {qa.x, qa.y, qa.z, qa.w};
            float kb_[4] = {kb.x, kb.y, kb.z, kb.w};
#pragma unroll
            for (int i = 0; i < 4; ++i)
#pragma unroll
                for (int j = 0; j < 4; ++j) s[i][j] += qa_[i] * kb_[j];
        }
        // mask invalid keys
        int kvalid = SS - k0;           // <64 only for last tile
        if (kvalid < 64) {
#pragma unroll
            for (int j = 0; j < 4; ++j)
                if (tx * 4 + j >= kvalid) {
#pragma unroll
                    for (int i = 0; i < 4; ++i) s[i][j] = -1e30f;
                }
        }
        // online softmax update (per query row; 16 lanes share a row)
        float alpha[4];
#pragma unroll
        for (int i = 0; i < 4; ++i) {
            float mx = fmaxf(fmaxf(s[i][0], s[i][1]), fmaxf(s[i][2], s[i][3]));
#pragma unroll
            for (int off = 1; off < 16; off <<= 1) mx = fmaxf(mx, __shfl_xor(mx, off));
            float mn = fmaxf(m[i], mx);
            alpha[i] = __expf(m[i] - mn);
            m[i] = mn;
            float ps = 0.f;
#pragma unroll
            for (int j = 0; j < 4; ++j) {
                float p = __expf(s[i][j] - mn);
                s[i][j] = p;
                ps += p;
            }
#pragma unroll
            for (int off = 1; off < 16; off <<= 1) ps += __shfl_xor(ps, off);
            l[i] = l[i] * alpha[i] + ps;
        }
        // write P fragment: Ps[q][k], float4 rows
#pragma unroll
        for (int i = 0; i < 4; ++i) {
            float4 pv = make_float4(s[i][0], s[i][1], s[i][2], s[i][3]);
            *reinterpret_cast<float4*>(&Ps[ty * 4 + i][tx * 4]) = pv;
        }
        __syncthreads();

        // O update: rows = queries ty*4.., cols = dims tx*4..
#pragma unroll
        for (int i = 0; i < 4; ++i)
#pragma unroll
            for (int j = 0; j < 4; ++j) O[i][j] *= alpha[i];
        for (int k4 = 0; k4 < 16; ++k4) {
            float4 p0 = *reinterpret_cast<const float4*>(&Ps[ty * 4 + 0][k4 * 4]);
            float4 p1 = *reinterpret_cast<const float4*>(&Ps[ty * 4 + 1][k4 * 4]);
            float4 p2 = *reinterpret_cast<const float4*>(&Ps[ty * 4 + 2][k4 * 4]);
            float4 p3 = *reinterpret_cast<const float4*>(&Ps[ty * 4 + 3][k4 * 4]);
            float pr[4][4] = {{p0.x, p0.y, p0.z, p0.w},
                              {p1.x, p1.y, p1.z, p1.w},
                              {p2.x, p2.y, p2.z, p2.w},
                              {p3.x, p3.y, p3.z, p3.w}};
#pragma unroll
            for (int kk = 0; kk < 4; ++kk) {
                float4 vb = *reinterpret_cast<const float4*>(&Vs[k4 * 4 + kk][tx * 4]);
                float vb_[4] = {vb.x, vb.y, vb.z, vb.w};
#pragma unroll
                for (int i = 0; i < 4; ++i)
#pragma unroll
                    for (int j = 0; j < 4; ++j) O[i][j] += pr[i][kk] * vb_[j];
            }
        }
    }

    // epilogue: O /= l, store (B,S,DIM)
#pragma unroll
    for (int i = 0; i < 4; ++i) {
        int gq = q0 + ty * 4 + i;
        if (gq >= SS) continue;
        float inv = 1.f / l[i];
        float4 ov = make_float4(O[i][0] * inv, O[i][1] * inv, O[i][2] * inv, O[i][3] * inv);
        *reinterpret_cast<float4*>(o + ((size_t)b * SS + gq) * DIM + h * DH + tx * 4) = ov;
    }
}

// ---------------------------------------------------------------------------
// Output: x[:, 1:, :] -> out (B, NP, DIM)
// ---------------------------------------------------------------------------
__global__ __launch_bounds__(256) void copy_out_k(const float* __restrict__ x,
                                                  float* __restrict__ out) {
    int idx = blockIdx.x * 256 + threadIdx.x;
    const int total = BB * NP * DIM;
    if (idx >= total) return;
    int b = idx / (NP * DIM);
    int r = idx % (NP * DIM);
    int n = r / DIM;
    int d = r % DIM;
    out[idx] = x[((size_t)b * SS + 1 + n) * DIM + d];
}

// ---------------------------------------------------------------------------
extern "C" void kernel_launch(void* const* d_in, const int* in_sizes, int n_in,
                              void* d_out, int out_size, void* d_ws, size_t ws_size,
                              hipStream_t stream) {
    const float* img     = (const float*)d_in[0];
    const float* pos     = (const float*)d_in[1];
    const float* cls     = (const float*)d_in[2];
    const float* patch_w = (const float*)d_in[3];
    const float* patch_b = (const float*)d_in[4];
    const float* ln1_g   = (const float*)d_in[5];
    const float* ln1_b   = (const float*)d_in[6];
    const float* qkv_w   = (const float*)d_in[7];
    const float* out_w   = (const float*)d_in[8];
    const float* out_b   = (const float*)d_in[9];
    const float* ln2_g   = (const float*)d_in[10];
    const float* ln2_b   = (const float*)d_in[11];
    const float* ff1_w   = (const float*)d_in[12];
    const float* ff1_b   = (const float*)d_in[13];
    const float* ff2_w   = (const float*)d_in[14];
    const float* ff2_b   = (const float*)d_in[15];
    float* out = (float*)d_out;

    // workspace layout (floats): x | y | t1 | big
    float* ws = (float*)d_ws;
    float* x   = ws;
    float* y   = x + (size_t)BS * DIM;
    float* t1  = y + (size_t)BS * DIM;
    float* big = t1 + (size_t)BS * DIM;   // BS * MLP floats

    const int threads = 256;
    // 1. patchify into big
    {
        int tot = BB * NP * PD;
        patchify_k<<<(tot + 255) / 256, threads, 0, stream>>>(img, big);
    }
    // 2. patch embed: t1 = Xp @ patch_w + patch_b
    gemm_k<0><<<dim3(DIM / 64, (BB * NP) / 64), threads, 0, stream>>>(
        big, patch_w, patch_b, t1, BB * NP, DIM, PD);
    // 3. assemble x with cls token + positional embedding
    {
        int tot = BB * SS * DIM;
        build_x_k<<<(tot + 255) / 256, threads, 0, stream>>>(t1, cls, pos, x);
    }

    const int mblk = (BS + 63) / 64;   // 73
    for (int l = 0; l < DEPTH; ++l) {
        ln_k<<<BS, threads, 0, stream>>>(x, ln1_g + l * DIM, ln1_b + l * DIM, y);
        gemm_k<0><<<dim3((3 * DIM) / 64, mblk), threads, 0, stream>>>(
            y, qkv_w + (size_t)l * DIM * 3 * DIM, nullptr, big, BS, 3 * DIM, DIM);
        // flash attention -> t1
        fattn_k<<<dim3(BB * HEADS, (SS + 63) / 64), threads, 0, stream>>>(big, t1);
        gemm_k<2><<<dim3(DIM / 64, mblk), threads, 0, stream>>>(
            t1, out_w + (size_t)l * DIM * DIM, out_b + l * DIM, x, BS, DIM, DIM);
        ln_k<<<BS, threads, 0, stream>>>(x, ln2_g + l * DIM, ln2_b + l * DIM, y);
        gemm_k<1><<<dim3(MLP / 64, mblk), threads, 0, stream>>>(
            y, ff1_w + (size_t)l * DIM * MLP, ff1_b + l * MLP, big, BS, MLP, DIM);
        gemm_k<2><<<dim3(DIM / 64, mblk), threads, 0, stream>>>(
            big, ff2_w + (size_t)l * MLP * DIM, ff2_b + l * DIM, x, BS, DIM, MLP);
    }

    {
        int tot = BB * NP * DIM;
        copy_out_k<<<(tot + 255) / 256, threads, 0, stream>>>(x, out);
    }
}

// Round 3
// 3806.927 us; speedup vs baseline: 6.7369x; 2.5222x over previous
//
#include <hip/hip_runtime.h>
#include <hip/hip_bf16.h>
#include <math.h>

// Problem constants (ViT): B=8, C=3, H=384, P=16 -> 24x24=576 patches, S=577
#define BB 8
#define CC 3
#define HH 384
#define PP 16
#define HP 24            // H/P
#define NP 576           // patches per image
#define PD 768           // patch dim = C*P*P
#define DIM 768
#define DEPTH 8
#define HEADS 12
#define DH 64            // DIM/HEADS
#define MLP 3072
#define SS 577           // seq len = NP+1
#define BS (BB*SS)       // 4616 rows
#define MPAD 4736        // 37*128, padded row count for GEMM A-operands
#define LN_EPS 1e-5f
#define NKT 10           // ceil(577/64) key tiles

typedef __attribute__((ext_vector_type(8))) short s8v;   // 8 bf16 = 4 VGPRs
typedef __attribute__((ext_vector_type(4))) float f4v;   // MFMA accum

__device__ __forceinline__ float bf2f(unsigned short s) {
    union { unsigned u; float f; } x;
    x.u = ((unsigned)s) << 16;
    return x.f;
}
__device__ __forceinline__ unsigned short f2bfu(float f) {
    __hip_bfloat16 h = __float2bfloat16(f);
    return *reinterpret_cast<unsigned short*>(&h);
}

// async global->LDS, 16B per lane; LDS dest = base + lane*16 (wave-uniform base)
__device__ __forceinline__ void async16(void* lds, const void* g) {
    __builtin_amdgcn_global_load_lds(
        (const __attribute__((address_space(1))) void*)(uintptr_t)g,
        (__attribute__((address_space(3))) void*)(unsigned)(uintptr_t)lds,
        16, 0, 0);
}

// ---------------------------------------------------------------------------
// Patchify: img (B,C,H,H) -> Xp_bf (B*NP, PD) bf16, vec index (p1*P+p2)*C + c
// ---------------------------------------------------------------------------
__global__ __launch_bounds__(256) void patchify_k(const float* __restrict__ img,
                                                  unsigned short* __restrict__ xp) {
    int idx = blockIdx.x * 256 + threadIdx.x;
    const int total = BB * NP * PD;
    if (idx >= total) return;
    int b = idx / (NP * PD);
    int r = idx % (NP * PD);
    int n = r / PD;
    int j = r % PD;
    int c  = j % CC;
    int t  = j / CC;
    int p2 = t % PP;
    int p1 = t / PP;
    int hh = n / HP;
    int ww = n % HP;
    int row = hh * PP + p1;
    int col = ww * PP + p2;
    xp[idx] = f2bfu(img[(((size_t)b * CC + c) * HH + row) * HH + col]);
}

// ---------------------------------------------------------------------------
// Weight convert + transpose: W (K,N) fp32 -> Wt (N,K) bf16.  K,N % 32 == 0.
// ---------------------------------------------------------------------------
__global__ __launch_bounds__(256) void convT_k(const float* __restrict__ W,
                                               unsigned short* __restrict__ Wt,
                                               int K, int N) {
    __shared__ float t[32][33];
    int tx = threadIdx.x & 31, ty = threadIdx.x >> 5;   // 32 x 8
    int n0 = blockIdx.x * 32, k0 = blockIdx.y * 32;
#pragma unroll
    for (int i = 0; i < 32; i += 8)
        t[ty + i][tx] = W[(size_t)(k0 + ty + i) * N + n0 + tx];
    __syncthreads();
#pragma unroll
    for (int i = 0; i < 32; i += 8)
        Wt[(size_t)(n0 + ty + i) * K + k0 + tx] = f2bfu(t[tx][ty + i]);
}

// ---------------------------------------------------------------------------
// Build residual stream x (B,S,DIM) fp32
// ---------------------------------------------------------------------------
__global__ __launch_bounds__(256) void build_x_k(const float* __restrict__ pe,
                                                 const float* __restrict__ cls,
                                                 const float* __restrict__ pos,
                                                 float* __restrict__ x) {
    int idx = blockIdx.x * 256 + threadIdx.x;
    const int total = BB * SS * DIM;
    if (idx >= total) return;
    int b = idx / (SS * DIM);
    int r = idx % (SS * DIM);
    int i = r / DIM;
    int d = r % DIM;
    float p = pos[i * DIM + d];
    float v = (i == 0) ? cls[d] : pe[((size_t)b * NP + (i - 1)) * DIM + d];
    x[idx] = v + p;
}

// ---------------------------------------------------------------------------
// LayerNorm: x fp32 -> y bf16. One block per row.
// ---------------------------------------------------------------------------
__global__ __launch_bounds__(256) void ln_k(const float* __restrict__ x,
                                            const float* __restrict__ g,
                                            const float* __restrict__ bt,
                                            unsigned short* __restrict__ y) {
    __shared__ float sm[8];
    int row = blockIdx.x, tid = threadIdx.x;
    const float* xr = x + (size_t)row * DIM;
    float v0 = xr[tid], v1 = xr[tid + 256], v2 = xr[tid + 512];
    float s = v0 + v1 + v2;
    for (int o = 32; o; o >>= 1) s += __shfl_xor(s, o);
    if ((tid & 63) == 0) sm[tid >> 6] = s;
    __syncthreads();
    float mean = (sm[0] + sm[1] + sm[2] + sm[3]) * (1.f / 768.f);
    float q0 = v0 - mean, q1 = v1 - mean, q2 = v2 - mean;
    float s2 = q0 * q0 + q1 * q1 + q2 * q2;
    for (int o = 32; o; o >>= 1) s2 += __shfl_xor(s2, o);
    if ((tid & 63) == 0) sm[4 + (tid >> 6)] = s2;
    __syncthreads();
    float var = (sm[4] + sm[5] + sm[6] + sm[7]) * (1.f / 768.f);
    float rstd = rsqrtf(var + LN_EPS);
    unsigned short* yr = y + (size_t)row * DIM;
    yr[tid]       = f2bfu(q0 * rstd * g[tid]       + bt[tid]);
    yr[tid + 256] = f2bfu(q1 * rstd * g[tid + 256] + bt[tid + 256]);
    yr[tid + 512] = f2bfu(q2 * rstd * g[tid + 512] + bt[tid + 512]);
}

// ---------------------------------------------------------------------------
// bf16 MFMA GEMM (m97 structure): C = epilogue(A @ Bt^T + bias)
//   A:  (Mpad, K) bf16 row-major (only rows < M stored)
//   Bt: (N, K)   bf16 row-major (pre-transposed weight)
//   OP 0: bf16 out = acc + bias      (bias may be null)
//   OP 1: bf16 out = gelu(acc+bias)
//   OP 2: fp32 C  += acc + bias      (residual)
//   OP 3: fp32 out = acc + bias
// 128x128 tile, 256 thr (4 waves, 2x2), 16x16x32 MFMA, BK=32, async staging.
// ---------------------------------------------------------------------------
template <int OP>
__global__ __launch_bounds__(256) void mgemm_k(const unsigned short* __restrict__ A,
                                               const unsigned short* __restrict__ Bt,
                                               const float* __restrict__ bias,
                                               void* __restrict__ Cv,
                                               int M, int N, int K) {
    __shared__ unsigned short Al[128 * 32];
    __shared__ unsigned short Bl[128 * 32];
    int tid = threadIdx.x;
    int wv = tid >> 6, lane = tid & 63;
    int quad = lane >> 4, l16 = lane & 15;
    int m0 = blockIdx.y * 128, n0 = blockIdx.x * 128;
    int wm = (wv >> 1) * 64, wn = (wv & 1) * 64;
    int rg = lane >> 2;            // row within 16-row staging group
    int kc = (lane & 3) * 8;       // k element offset (8 bf16 = 16B)

    f4v acc[4][4];
    const f4v zero = {0.f, 0.f, 0.f, 0.f};
#pragma unroll
    for (int i = 0; i < 4; ++i)
#pragma unroll
        for (int j = 0; j < 4; ++j) acc[i][j] = zero;

    for (int k0 = 0; k0 < K; k0 += 32) {
        __syncthreads();   // previous iteration's readers done
#pragma unroll
        for (int gg = 0; gg < 2; ++gg) {
            int g = wv + gg * 4;                // staging group 0..7
            const unsigned short* ga = A + (size_t)(m0 + g * 16 + rg) * K + k0 + kc;
            async16(&Al[g * 512], ga);
            const unsigned short* gb = Bt + (size_t)(n0 + g * 16 + rg) * K + k0 + kc;
            async16(&Bl[g * 512], gb);
        }
        __syncthreads();   // drains vmcnt then barrier

        s8v af[4], bfr[4];
#pragma unroll
        for (int i = 0; i < 4; ++i)
            af[i] = *reinterpret_cast<const s8v*>(&Al[(wm + i * 16 + l16) * 32 + quad * 8]);
#pragma unroll
        for (int j = 0; j < 4; ++j)
            bfr[j] = *reinterpret_cast<const s8v*>(&Bl[(wn + j * 16 + l16) * 32 + quad * 8]);
#pragma unroll
        for (int i = 0; i < 4; ++i)
#pragma unroll
            for (int j = 0; j < 4; ++j)
                acc[i][j] = __builtin_amdgcn_mfma_f32_16x16x32_bf16(af[i], bfr[j], acc[i][j], 0, 0, 0);
    }

    // epilogue: C/D layout col=lane&15, row=quad*4+reg
#pragma unroll
    for (int j = 0; j < 4; ++j) {
        int col = n0 + wn + j * 16 + l16;
        float bj = bias ? bias[col] : 0.f;
#pragma unroll
        for (int i = 0; i < 4; ++i) {
#pragma unroll
            for (int r = 0; r < 4; ++r) {
                int row = m0 + wm + i * 16 + quad * 4 + r;
                if (row >= M) continue;
                float v = acc[i][j][r] + bj;
                size_t idx = (size_t)row * N + col;
                if (OP == 0) {
                    ((unsigned short*)Cv)[idx] = f2bfu(v);
                } else if (OP == 1) {
                    v = 0.5f * v * (1.f + erff(v * 0.70710678118654752f));
                    ((unsigned short*)Cv)[idx] = f2bfu(v);
                } else if (OP == 2) {
                    float* C = (float*)Cv;
                    C[idx] += v;
                } else {
                    ((float*)Cv)[idx] = v;
                }
            }
        }
    }
}

// ---------------------------------------------------------------------------
// Flash-style attention, fp32 math, bf16 I/O. One block per (b*h, q-tile 64).
// No 1/sqrt(d) scale (faithful). qkv: (B,S,3*DIM) bf16; out: (B,S,DIM) bf16.
// ---------------------------------------------------------------------------
__global__ __launch_bounds__(256) void fattn_k(const unsigned short* __restrict__ qkv,
                                               unsigned short* __restrict__ o) {
    __shared__ float Qs[64][64];   // [d][q]
    __shared__ float Ks[64][64];   // [d][k]
    __shared__ float Vs[64][64];   // [k][d]
    __shared__ float Ps[64][64];   // [q][k]

    int bh = blockIdx.x;
    int b = bh / HEADS, h = bh % HEADS;
    int q0 = blockIdx.y * 64;
    int tid = threadIdx.x;
    int tx = tid & 15, ty = tid >> 4;

    const size_t stride = 3 * DIM;
    const unsigned short* qbase = qkv + (size_t)b * SS * stride + h * DH;
    const unsigned short* kbase = qbase + DIM;
    const unsigned short* vbase = qbase + 2 * DIM;

#pragma unroll
    for (int rr = 0; rr < 4; ++rr) {
        int r = rr * 16 + ty;
        int gq = q0 + r;
        float4 v;
        if (gq < SS) {
            ushort4 u = *reinterpret_cast<const ushort4*>(qbase + (size_t)gq * stride + tx * 4);
            v = make_float4(bf2f(u.x), bf2f(u.y), bf2f(u.z), bf2f(u.w));
        } else v = make_float4(0.f, 0.f, 0.f, 0.f);
        Qs[tx * 4 + 0][r] = v.x;
        Qs[tx * 4 + 1][r] = v.y;
        Qs[tx * 4 + 2][r] = v.z;
        Qs[tx * 4 + 3][r] = v.w;
    }

    float m[4], l[4], O[4][4];
#pragma unroll
    for (int i = 0; i < 4; ++i) {
        m[i] = -INFINITY; l[i] = 0.f;
#pragma unroll
        for (int j = 0; j < 4; ++j) O[i][j] = 0.f;
    }

    for (int t = 0; t < NKT; ++t) {
        int k0 = t * 64;
        __syncthreads();
#pragma unroll
        for (int rr = 0; rr < 4; ++rr) {
            int r = rr * 16 + ty;
            int gk = k0 + r;
            float4 kv, vv;
            if (gk < SS) {
                ushort4 uk = *reinterpret_cast<const ushort4*>(kbase + (size_t)gk * stride + tx * 4);
                ushort4 uv = *reinterpret_cast<const ushort4*>(vbase + (size_t)gk * stride + tx * 4);
                kv = make_float4(bf2f(uk.x), bf2f(uk.y), bf2f(uk.z), bf2f(uk.w));
                vv = make_float4(bf2f(uv.x), bf2f(uv.y), bf2f(uv.z), bf2f(uv.w));
            } else {
                kv = make_float4(0.f, 0.f, 0.f, 0.f);
                vv = make_float4(0.f, 0.f, 0.f, 0.f);
            }
            Ks[tx * 4 + 0][r] = kv.x;
            Ks[tx * 4 + 1][r] = kv.y;
            Ks[tx * 4 + 2][r] = kv.z;
            Ks[tx * 4 + 3][r] = kv.w;
            *reinterpret_cast<float4*>(&Vs[r][tx * 4]) = vv;
        }
        __syncthreads();

        float s[4][4];
#pragma unroll
        for (int i = 0; i < 4; ++i)
#pragma unroll
            for (int j = 0; j < 4; ++j) s[i][j] = 0.f;
        for (int d = 0; d < 64; ++d) {
            float4 qa = *reinterpret_cast<const float4*>(&Qs[d][ty * 4]);
            float4 kb = *reinterpret_cast<const float4*>(&Ks[d][tx * 4]);
            float qa_[4] = {qa.x, qa.y, qa.z, qa.w};
            float kb_[4] = {kb.x, kb.y, kb.z, kb.w};
#pragma unroll
            for (int i = 0; i < 4; ++i)
#pragma unroll
                for (int j = 0; j < 4; ++j) s[i][j] += qa_[i] * kb_[j];
        }
        int kvalid = SS - k0;
        if (kvalid < 64) {
#pragma unroll
            for (int j = 0; j < 4; ++j)
                if (tx * 4 + j >= kvalid) {
#pragma unroll
                    for (int i = 0; i < 4; ++i) s[i][j] = -1e30f;
                }
        }
        float alpha[4];
#pragma unroll
        for (int i = 0; i < 4; ++i) {
            float mx = fmaxf(fmaxf(s[i][0], s[i][1]), fmaxf(s[i][2], s[i][3]));
#pragma unroll
            for (int off = 1; off < 16; off <<= 1) mx = fmaxf(mx, __shfl_xor(mx, off));
            float mn = fmaxf(m[i], mx);
            alpha[i] = __expf(m[i] - mn);
            m[i] = mn;
            float ps = 0.f;
#pragma unroll
            for (int j = 0; j < 4; ++j) {
                float p = __expf(s[i][j] - mn);
                s[i][j] = p;
                ps += p;
            }
#pragma unroll
            for (int off = 1; off < 16; off <<= 1) ps += __shfl_xor(ps, off);
            l[i] = l[i] * alpha[i] + ps;
        }
#pragma unroll
        for (int i = 0; i < 4; ++i) {
            float4 pv = make_float4(s[i][0], s[i][1], s[i][2], s[i][3]);
            *reinterpret_cast<float4*>(&Ps[ty * 4 + i][tx * 4]) = pv;
        }
        __syncthreads();

#pragma unroll
        for (int i = 0; i < 4; ++i)
#pragma unroll
            for (int j = 0; j < 4; ++j) O[i][j] *= alpha[i];
        for (int k4 = 0; k4 < 16; ++k4) {
            float4 p0 = *reinterpret_cast<const float4*>(&Ps[ty * 4 + 0][k4 * 4]);
            float4 p1 = *reinterpret_cast<const float4*>(&Ps[ty * 4 + 1][k4 * 4]);
            float4 p2 = *reinterpret_cast<const float4*>(&Ps[ty * 4 + 2][k4 * 4]);
            float4 p3 = *reinterpret_cast<const float4*>(&Ps[ty * 4 + 3][k4 * 4]);
            float pr[4][4] = {{p0.x, p0.y, p0.z, p0.w},
                              {p1.x, p1.y, p1.z, p1.w},
                              {p2.x, p2.y, p2.z, p2.w},
                              {p3.x, p3.y, p3.z, p3.w}};
#pragma unroll
            for (int kk = 0; kk < 4; ++kk) {
                float4 vb = *reinterpret_cast<const float4*>(&Vs[k4 * 4 + kk][tx * 4]);
                float vb_[4] = {vb.x, vb.y, vb.z, vb.w};
#pragma unroll
                for (int i = 0; i < 4; ++i)
#pragma unroll
                    for (int j = 0; j < 4; ++j) O[i][j] += pr[i][kk] * vb_[j];
            }
        }
    }

#pragma unroll
    for (int i = 0; i < 4; ++i) {
        int gq = q0 + ty * 4 + i;
        if (gq >= SS) continue;
        float inv = 1.f / l[i];
        ushort4 o4;
        o4.x = f2bfu(O[i][0] * inv);
        o4.y = f2bfu(O[i][1] * inv);
        o4.z = f2bfu(O[i][2] * inv);
        o4.w = f2bfu(O[i][3] * inv);
        *reinterpret_cast<ushort4*>(o + ((size_t)b * SS + gq) * DIM + h * DH + tx * 4) = o4;
    }
}

// ---------------------------------------------------------------------------
// Output: x[:, 1:, :] fp32 -> out (B, NP, DIM)
// ---------------------------------------------------------------------------
__global__ __launch_bounds__(256) void copy_out_k(const float* __restrict__ x,
                                                  float* __restrict__ out) {
    int idx = blockIdx.x * 256 + threadIdx.x;
    const int total = BB * NP * DIM;
    if (idx >= total) return;
    int b = idx / (NP * DIM);
    int r = idx % (NP * DIM);
    int n = r / DIM;
    int d = r % DIM;
    out[idx] = x[((size_t)b * SS + 1 + n) * DIM + d];
}

// ---------------------------------------------------------------------------
extern "C" void kernel_launch(void* const* d_in, const int* in_sizes, int n_in,
                              void* d_out, int out_size, void* d_ws, size_t ws_size,
                              hipStream_t stream) {
    const float* img     = (const float*)d_in[0];
    const float* pos     = (const float*)d_in[1];
    const float* cls     = (const float*)d_in[2];
    const float* patch_w = (const float*)d_in[3];
    const float* patch_b = (const float*)d_in[4];
    const float* ln1_g   = (const float*)d_in[5];
    const float* ln1_b   = (const float*)d_in[6];
    const float* qkv_w   = (const float*)d_in[7];
    const float* out_w   = (const float*)d_in[8];
    const float* out_b   = (const float*)d_in[9];
    const float* ln2_g   = (const float*)d_in[10];
    const float* ln2_b   = (const float*)d_in[11];
    const float* ff1_w   = (const float*)d_in[12];
    const float* ff1_b   = (const float*)d_in[13];
    const float* ff2_w   = (const float*)d_in[14];
    const float* ff2_b   = (const float*)d_in[15];
    float* out = (float*)d_out;

    // workspace layout
    char* base = (char*)d_ws;
    float* x = (float*)base;                          base += (size_t)BS * DIM * 4;      // 14.18 MB
    unsigned short* y_bf   = (unsigned short*)base;   base += (size_t)MPAD * DIM * 2;    // 7.27 MB
    unsigned short* t1_bf  = (unsigned short*)base;   base += (size_t)MPAD * DIM * 2;    // 7.27 MB
    unsigned short* qkv_bf = (unsigned short*)base;   base += (size_t)MPAD * 3 * DIM * 2;// 21.8 MB
    unsigned short* hid_bf = (unsigned short*)base;   base += (size_t)MPAD * MLP * 2;    // 29.1 MB
    unsigned short* xp_bf  = (unsigned short*)base;   base += (size_t)BB * NP * PD * 2;  // 7.08 MB
    unsigned short* wt_bf  = (unsigned short*)base;   base += (size_t)MLP * DIM * 2;     // 4.72 MB
    float* pe_f32 = (float*)hid_bf;   // patch-embed fp32 out, alias (consumed pre-loop)

    const int threads = 256;
    const int mblk = (BS + 127) / 128;   // 37

    // 1. patchify (bf16)
    patchify_k<<<(BB * NP * PD + 255) / 256, threads, 0, stream>>>(img, xp_bf);
    // 2. patch embed: pe = Xp @ patch_w + patch_b  (fp32 out)
    convT_k<<<dim3(DIM / 32, PD / 32), threads, 0, stream>>>(patch_w, wt_bf, PD, DIM);
    mgemm_k<3><<<dim3(DIM / 128, (BB * NP) / 128), threads, 0, stream>>>(
        xp_bf, wt_bf, patch_b, pe_f32, BB * NP, DIM, PD);
    // 3. assemble x
    build_x_k<<<(BB * SS * DIM + 255) / 256, threads, 0, stream>>>(pe_f32, cls, pos, x);

    for (int l = 0; l < DEPTH; ++l) {
        ln_k<<<BS, threads, 0, stream>>>(x, ln1_g + l * DIM, ln1_b + l * DIM, y_bf);
        // qkv = y @ wqkv (bf16 out, no bias)
        convT_k<<<dim3(3 * DIM / 32, DIM / 32), threads, 0, stream>>>(
            qkv_w + (size_t)l * DIM * 3 * DIM, wt_bf, DIM, 3 * DIM);
        mgemm_k<0><<<dim3(3 * DIM / 128, mblk), threads, 0, stream>>>(
            y_bf, wt_bf, nullptr, qkv_bf, BS, 3 * DIM, DIM);
        // attention -> t1 (bf16)
        fattn_k<<<dim3(BB * HEADS, (SS + 63) / 64), threads, 0, stream>>>(qkv_bf, t1_bf);
        // x += t1 @ out_w + out_b
        convT_k<<<dim3(DIM / 32, DIM / 32), threads, 0, stream>>>(
            out_w + (size_t)l * DIM * DIM, wt_bf, DIM, DIM);
        mgemm_k<2><<<dim3(DIM / 128, mblk), threads, 0, stream>>>(
            t1_bf, wt_bf, out_b + l * DIM, x, BS, DIM, DIM);
        ln_k<<<BS, threads, 0, stream>>>(x, ln2_g + l * DIM, ln2_b + l * DIM, y_bf);
        // hid = gelu(y @ w1 + b1) (bf16)
        convT_k<<<dim3(MLP / 32, DIM / 32), threads, 0, stream>>>(
            ff1_w + (size_t)l * DIM * MLP, wt_bf, DIM, MLP);
        mgemm_k<1><<<dim3(MLP / 128, mblk), threads, 0, stream>>>(
            y_bf, wt_bf, ff1_b + l * MLP, hid_bf, BS, MLP, DIM);
        // x += hid @ w2 + b2
        convT_k<<<dim3(DIM / 32, MLP / 32), threads, 0, stream>>>(
            ff2_w + (size_t)l * MLP * DIM, wt_bf, MLP, DIM);
        mgemm_k<2><<<dim3(DIM / 128, mblk), threads, 0, stream>>>(
            hid_bf, wt_bf, ff2_b + l * DIM, x, BS, DIM, MLP);
    }

    copy_out_k<<<(BB * NP * DIM + 255) / 256, threads, 0, stream>>>(x, out);
}

// Round 4
// 2610.724 us; speedup vs baseline: 9.8236x; 1.4582x over previous
//
#include <hip/hip_runtime.h>
#include <hip/hip_bf16.h>
#include <math.h>

// Problem constants (ViT): B=8, C=3, H=384, P=16 -> 24x24=576 patches, S=577
#define BB 8
#define CC 3
#define HH 384
#define PP 16
#define HP 24            // H/P
#define NP 576           // patches per image
#define PD 768           // patch dim = C*P*P
#define DIM 768
#define DEPTH 8
#define HEADS 12
#define DH 64            // DIM/HEADS
#define MLP 3072
#define SS 577           // seq len = NP+1
#define BS (BB*SS)       // 4616 rows
#define MPAD 4736        // 37*128, padded row count for GEMM A-operands
#define LN_EPS 1e-5f
#define NKT 10           // ceil(577/64) key tiles
#define QW (3*DIM)       // qkv row width 2304

typedef __attribute__((ext_vector_type(8))) short s8v;   // 8 bf16 = 4 VGPRs
typedef __attribute__((ext_vector_type(4))) float f4v;   // MFMA accum

__device__ __forceinline__ float bf2f(unsigned short s) {
    union { unsigned u; float f; } x;
    x.u = ((unsigned)s) << 16;
    return x.f;
}
__device__ __forceinline__ unsigned short f2bfu(float f) {
    __hip_bfloat16 h = __float2bfloat16(f);
    return *reinterpret_cast<unsigned short*>(&h);
}

// async global->LDS, 16B per lane; LDS dest = base + lane*16 (wave-uniform base)
__device__ __forceinline__ void async16(void* lds, const void* g) {
    __builtin_amdgcn_global_load_lds(
        (const __attribute__((address_space(1))) void*)(uintptr_t)g,
        (__attribute__((address_space(3))) void*)(unsigned)(uintptr_t)lds,
        16, 0, 0);
}

// ---------------------------------------------------------------------------
// Patchify: img (B,C,H,H) -> Xp_bf (B*NP, PD) bf16, vec index (p1*P+p2)*C + c
// ---------------------------------------------------------------------------
__global__ __launch_bounds__(256) void patchify_k(const float* __restrict__ img,
                                                  unsigned short* __restrict__ xp) {
    int idx = blockIdx.x * 256 + threadIdx.x;
    const int total = BB * NP * PD;
    if (idx >= total) return;
    int b = idx / (NP * PD);
    int r = idx % (NP * PD);
    int n = r / PD;
    int j = r % PD;
    int c  = j % CC;
    int t  = j / CC;
    int p2 = t % PP;
    int p1 = t / PP;
    int hh = n / HP;
    int ww = n % HP;
    int row = hh * PP + p1;
    int col = ww * PP + p2;
    xp[idx] = f2bfu(img[(((size_t)b * CC + c) * HH + row) * HH + col]);
}

// ---------------------------------------------------------------------------
// Weight convert + transpose: W (K,N) fp32 -> Wt (N,K) bf16.  K,N % 32 == 0.
// ---------------------------------------------------------------------------
__global__ __launch_bounds__(256) void convT_k(const float* __restrict__ W,
                                               unsigned short* __restrict__ Wt,
                                               int K, int N) {
    __shared__ float t[32][33];
    int tx = threadIdx.x & 31, ty = threadIdx.x >> 5;   // 32 x 8
    int n0 = blockIdx.x * 32, k0 = blockIdx.y * 32;
#pragma unroll
    for (int i = 0; i < 32; i += 8)
        t[ty + i][tx] = W[(size_t)(k0 + ty + i) * N + n0 + tx];
    __syncthreads();
#pragma unroll
    for (int i = 0; i < 32; i += 8)
        Wt[(size_t)(n0 + ty + i) * K + k0 + tx] = f2bfu(t[tx][ty + i]);
}

// ---------------------------------------------------------------------------
// Build residual stream x (B,S,DIM) fp32
// ---------------------------------------------------------------------------
__global__ __launch_bounds__(256) void build_x_k(const float* __restrict__ pe,
                                                 const float* __restrict__ cls,
                                                 const float* __restrict__ pos,
                                                 float* __restrict__ x) {
    int idx = blockIdx.x * 256 + threadIdx.x;
    const int total = BB * SS * DIM;
    if (idx >= total) return;
    int b = idx / (SS * DIM);
    int r = idx % (SS * DIM);
    int i = r / DIM;
    int d = r % DIM;
    float p = pos[i * DIM + d];
    float v = (i == 0) ? cls[d] : pe[((size_t)b * NP + (i - 1)) * DIM + d];
    x[idx] = v + p;
}

// ---------------------------------------------------------------------------
// LayerNorm: x fp32 -> y bf16. One block per row.
// ---------------------------------------------------------------------------
__global__ __launch_bounds__(256) void ln_k(const float* __restrict__ x,
                                            const float* __restrict__ g,
                                            const float* __restrict__ bt,
                                            unsigned short* __restrict__ y) {
    __shared__ float sm[8];
    int row = blockIdx.x, tid = threadIdx.x;
    const float* xr = x + (size_t)row * DIM;
    float v0 = xr[tid], v1 = xr[tid + 256], v2 = xr[tid + 512];
    float s = v0 + v1 + v2;
    for (int o = 32; o; o >>= 1) s += __shfl_xor(s, o);
    if ((tid & 63) == 0) sm[tid >> 6] = s;
    __syncthreads();
    float mean = (sm[0] + sm[1] + sm[2] + sm[3]) * (1.f / 768.f);
    float q0 = v0 - mean, q1 = v1 - mean, q2 = v2 - mean;
    float s2 = q0 * q0 + q1 * q1 + q2 * q2;
    for (int o = 32; o; o >>= 1) s2 += __shfl_xor(s2, o);
    if ((tid & 63) == 0) sm[4 + (tid >> 6)] = s2;
    __syncthreads();
    float var = (sm[4] + sm[5] + sm[6] + sm[7]) * (1.f / 768.f);
    float rstd = rsqrtf(var + LN_EPS);
    unsigned short* yr = y + (size_t)row * DIM;
    yr[tid]       = f2bfu(q0 * rstd * g[tid]       + bt[tid]);
    yr[tid + 256] = f2bfu(q1 * rstd * g[tid + 256] + bt[tid + 256]);
    yr[tid + 512] = f2bfu(q2 * rstd * g[tid + 512] + bt[tid + 512]);
}

// ---------------------------------------------------------------------------
// bf16 MFMA GEMM (m97 structure): C = epilogue(A @ Bt^T + bias)
//   A:  (Mpad, K) bf16 row-major; Bt: (N, K) bf16 row-major
//   OP 0: bf16 out = acc + bias      (bias may be null)
//   OP 1: bf16 out = gelu(acc+bias)
//   OP 2: fp32 C  += acc + bias      (residual)
//   OP 3: fp32 out = acc + bias
// 128x128 tile, 256 thr (4 waves, 2x2), 16x16x32 MFMA, BK=32, async staging.
// ---------------------------------------------------------------------------
template <int OP>
__global__ __launch_bounds__(256) void mgemm_k(const unsigned short* __restrict__ A,
                                               const unsigned short* __restrict__ Bt,
                                               const float* __restrict__ bias,
                                               void* __restrict__ Cv,
                                               int M, int N, int K) {
    __shared__ unsigned short Al[128 * 32];
    __shared__ unsigned short Bl[128 * 32];
    int tid = threadIdx.x;
    int wv = tid >> 6, lane = tid & 63;
    int quad = lane >> 4, l16 = lane & 15;
    int m0 = blockIdx.y * 128, n0 = blockIdx.x * 128;
    int wm = (wv >> 1) * 64, wn = (wv & 1) * 64;
    int rg = lane >> 2;            // row within 16-row staging group
    int kc = (lane & 3) * 8;       // k element offset (8 bf16 = 16B)

    f4v acc[4][4];
    const f4v zero = {0.f, 0.f, 0.f, 0.f};
#pragma unroll
    for (int i = 0; i < 4; ++i)
#pragma unroll
        for (int j = 0; j < 4; ++j) acc[i][j] = zero;

    for (int k0 = 0; k0 < K; k0 += 32) {
        __syncthreads();
#pragma unroll
        for (int gg = 0; gg < 2; ++gg) {
            int g = wv + gg * 4;
            const unsigned short* ga = A + (size_t)(m0 + g * 16 + rg) * K + k0 + kc;
            async16(&Al[g * 512], ga);
            const unsigned short* gb = Bt + (size_t)(n0 + g * 16 + rg) * K + k0 + kc;
            async16(&Bl[g * 512], gb);
        }
        __syncthreads();

        s8v af[4], bfr[4];
#pragma unroll
        for (int i = 0; i < 4; ++i)
            af[i] = *reinterpret_cast<const s8v*>(&Al[(wm + i * 16 + l16) * 32 + quad * 8]);
#pragma unroll
        for (int j = 0; j < 4; ++j)
            bfr[j] = *reinterpret_cast<const s8v*>(&Bl[(wn + j * 16 + l16) * 32 + quad * 8]);
#pragma unroll
        for (int i = 0; i < 4; ++i)
#pragma unroll
            for (int j = 0; j < 4; ++j)
                acc[i][j] = __builtin_amdgcn_mfma_f32_16x16x32_bf16(af[i], bfr[j], acc[i][j], 0, 0, 0);
    }

#pragma unroll
    for (int j = 0; j < 4; ++j) {
        int col = n0 + wn + j * 16 + l16;
        float bj = bias ? bias[col] : 0.f;
#pragma unroll
        for (int i = 0; i < 4; ++i) {
#pragma unroll
            for (int r = 0; r < 4; ++r) {
                int row = m0 + wm + i * 16 + quad * 4 + r;
                if (row >= M) continue;
                float v = acc[i][j][r] + bj;
                size_t idx = (size_t)row * N + col;
                if (OP == 0) {
                    ((unsigned short*)Cv)[idx] = f2bfu(v);
                } else if (OP == 1) {
                    v = 0.5f * v * (1.f + erff(v * 0.70710678118654752f));
                    ((unsigned short*)Cv)[idx] = f2bfu(v);
                } else if (OP == 2) {
                    float* C = (float*)Cv;
                    C[idx] += v;
                } else {
                    ((float*)Cv)[idx] = v;
                }
            }
        }
    }
}

// ---------------------------------------------------------------------------
// MFMA flash attention (bf16, fp32 softmax). One block per (b*h, q-tile 64).
// 4 waves; wave w owns queries q0+w*16..+15. No 1/sqrt(d) scale (faithful).
// K staged [key][dim] (stride 72), V staged transposed [dim][key] (stride 72),
// P round-trips through per-wave LDS (C-layout -> A-layout transform).
// ---------------------------------------------------------------------------
__global__ __launch_bounds__(256) void mattn_k(const unsigned short* __restrict__ qkv,
                                               unsigned short* __restrict__ o) {
    __shared__ unsigned short Kl[64 * 72];
    __shared__ unsigned short Vt[64 * 72];
    __shared__ unsigned short Pw[4][16 * 72];

    int tid = threadIdx.x;
    int w = tid >> 6, lane = tid & 63, quad = lane >> 4, l16 = lane & 15;
    int bh = blockIdx.x;
    int b = bh / HEADS, h = bh % HEADS;
    int q0 = blockIdx.y * 64;

    // Q A-fragments in registers: A[m=l16][k=quad*8+j], two 32-dim chunks
    int qq = q0 + w * 16 + l16;
    if (qq > SS - 1) qq = SS - 1;
    const unsigned short* qp = qkv + (size_t)(b * SS + qq) * QW + h * DH + quad * 8;
    s8v aq0 = *reinterpret_cast<const s8v*>(qp);
    s8v aq1 = *reinterpret_cast<const s8v*>(qp + 32);

    float m[4], l[4];
    f4v O[4];
    const f4v zero = {0.f, 0.f, 0.f, 0.f};
#pragma unroll
    for (int r = 0; r < 4; ++r) { m[r] = -INFINITY; l[r] = 0.f; }
#pragma unroll
    for (int dg = 0; dg < 4; ++dg) O[dg] = zero;

    for (int t = 0; t < NKT; ++t) {
        int k0 = t * 64;
        __syncthreads();   // previous tile's readers done
        // stage K tile: Kl[key][dim], row stride 72
#pragma unroll
        for (int rr = 0; rr < 2; ++rr) {
            int cid = tid + rr * 256;
            int row = cid >> 3, cb = (cid & 7) * 8;
            s8v kv = *reinterpret_cast<const s8v*>(
                qkv + (size_t)(b * SS + k0 + row) * QW + DIM + h * DH + cb);
            *reinterpret_cast<s8v*>(&Kl[row * 72 + cb]) = kv;
        }
        // stage V transposed: Vt[dim][key], via 4x4 register transpose
        {
            int kb = (tid & 15) * 4, db = (tid >> 4) * 4;
            const unsigned short* vb = qkv + (size_t)(b * SS + k0 + kb) * QW + 2 * DIM + h * DH + db;
            ushort4 r0 = *reinterpret_cast<const ushort4*>(vb);
            ushort4 r1 = *reinterpret_cast<const ushort4*>(vb + QW);
            ushort4 r2 = *reinterpret_cast<const ushort4*>(vb + 2 * QW);
            ushort4 r3 = *reinterpret_cast<const ushort4*>(vb + 3 * QW);
            ushort4 w0 = {r0.x, r1.x, r2.x, r3.x};
            ushort4 w1 = {r0.y, r1.y, r2.y, r3.y};
            ushort4 w2 = {r0.z, r1.z, r2.z, r3.z};
            ushort4 w3 = {r0.w, r1.w, r2.w, r3.w};
            *reinterpret_cast<ushort4*>(&Vt[(db + 0) * 72 + kb]) = w0;
            *reinterpret_cast<ushort4*>(&Vt[(db + 1) * 72 + kb]) = w1;
            *reinterpret_cast<ushort4*>(&Vt[(db + 2) * 72 + kb]) = w2;
            *reinterpret_cast<ushort4*>(&Vt[(db + 3) * 72 + kb]) = w3;
        }
        __syncthreads();

        // S = Q K^T : 4 key groups of 16
        f4v s[4];
#pragma unroll
        for (int kk = 0; kk < 4; ++kk) {
            const unsigned short* kp = &Kl[(kk * 16 + l16) * 72 + quad * 8];
            s8v b0 = *reinterpret_cast<const s8v*>(kp);
            s8v b1 = *reinterpret_cast<const s8v*>(kp + 32);
            f4v z = zero;
            z = __builtin_amdgcn_mfma_f32_16x16x32_bf16(aq0, b0, z, 0, 0, 0);
            z = __builtin_amdgcn_mfma_f32_16x16x32_bf16(aq1, b1, z, 0, 0, 0);
            s[kk] = z;
        }
        // mask invalid keys (last tile): lane's key = kk*16 + l16
        int kvalid = SS - k0;
        if (kvalid < 64) {
#pragma unroll
            for (int kk = 0; kk < 4; ++kk)
                if (kk * 16 + l16 >= kvalid) {
                    f4v mk = {-1e30f, -1e30f, -1e30f, -1e30f};
                    s[kk] = mk;
                }
        }
        // online softmax per query row (row = quad*4+r), write P, rescale O
        float alpha[4];
#pragma unroll
        for (int r = 0; r < 4; ++r) {
            float mx = fmaxf(fmaxf(s[0][r], s[1][r]), fmaxf(s[2][r], s[3][r]));
#pragma unroll
            for (int off = 1; off < 16; off <<= 1) mx = fmaxf(mx, __shfl_xor(mx, off));
            float mn = fmaxf(m[r], mx);
            alpha[r] = __expf(m[r] - mn);
            m[r] = mn;
            float ps = 0.f;
#pragma unroll
            for (int kk = 0; kk < 4; ++kk) {
                float p = __expf(s[kk][r] - mn);
                ps += p;
                Pw[w][(quad * 4 + r) * 72 + kk * 16 + l16] = f2bfu(p);
            }
#pragma unroll
            for (int off = 1; off < 16; off <<= 1) ps += __shfl_xor(ps, off);
            l[r] = l[r] * alpha[r] + ps;
        }
#pragma unroll
        for (int dg = 0; dg < 4; ++dg)
#pragma unroll
            for (int r = 0; r < 4; ++r) O[dg][r] *= alpha[r];

        // O += P V : A = P (A-layout from LDS), B = V^T rows from Vt
        s8v ap0 = *reinterpret_cast<const s8v*>(&Pw[w][l16 * 72 + quad * 8]);
        s8v ap1 = *reinterpret_cast<const s8v*>(&Pw[w][l16 * 72 + 32 + quad * 8]);
#pragma unroll
        for (int dg = 0; dg < 4; ++dg) {
            const unsigned short* vp = &Vt[(dg * 16 + l16) * 72 + quad * 8];
            s8v bv0 = *reinterpret_cast<const s8v*>(vp);
            s8v bv1 = *reinterpret_cast<const s8v*>(vp + 32);
            O[dg] = __builtin_amdgcn_mfma_f32_16x16x32_bf16(ap0, bv0, O[dg], 0, 0, 0);
            O[dg] = __builtin_amdgcn_mfma_f32_16x16x32_bf16(ap1, bv1, O[dg], 0, 0, 0);
        }
    }

    // epilogue: O /= l, store bf16 (row = quad*4+r, col = dg*16+l16)
#pragma unroll
    for (int r = 0; r < 4; ++r) {
        int q = q0 + w * 16 + quad * 4 + r;
        if (q >= SS) continue;
        float inv = 1.f / l[r];
        unsigned short* op = o + (size_t)(b * SS + q) * DIM + h * DH + l16;
#pragma unroll
        for (int dg = 0; dg < 4; ++dg)
            op[dg * 16] = f2bfu(O[dg][r] * inv);
    }
}

// ---------------------------------------------------------------------------
// Output: x[:, 1:, :] fp32 -> out (B, NP, DIM)
// ---------------------------------------------------------------------------
__global__ __launch_bounds__(256) void copy_out_k(const float* __restrict__ x,
                                                  float* __restrict__ out) {
    int idx = blockIdx.x * 256 + threadIdx.x;
    const int total = BB * NP * DIM;
    if (idx >= total) return;
    int b = idx / (NP * DIM);
    int r = idx % (NP * DIM);
    int n = r / DIM;
    int d = r % DIM;
    out[idx] = x[((size_t)b * SS + 1 + n) * DIM + d];
}

// ---------------------------------------------------------------------------
extern "C" void kernel_launch(void* const* d_in, const int* in_sizes, int n_in,
                              void* d_out, int out_size, void* d_ws, size_t ws_size,
                              hipStream_t stream) {
    const float* img     = (const float*)d_in[0];
    const float* pos     = (const float*)d_in[1];
    const float* cls     = (const float*)d_in[2];
    const float* patch_w = (const float*)d_in[3];
    const float* patch_b = (const float*)d_in[4];
    const float* ln1_g   = (const float*)d_in[5];
    const float* ln1_b   = (const float*)d_in[6];
    const float* qkv_w   = (const float*)d_in[7];
    const float* out_w   = (const float*)d_in[8];
    const float* out_b   = (const float*)d_in[9];
    const float* ln2_g   = (const float*)d_in[10];
    const float* ln2_b   = (const float*)d_in[11];
    const float* ff1_w   = (const float*)d_in[12];
    const float* ff1_b   = (const float*)d_in[13];
    const float* ff2_w   = (const float*)d_in[14];
    const float* ff2_b   = (const float*)d_in[15];
    float* out = (float*)d_out;

    // workspace layout
    char* base = (char*)d_ws;
    float* x = (float*)base;                          base += (size_t)BS * DIM * 4;
    unsigned short* y_bf   = (unsigned short*)base;   base += (size_t)MPAD * DIM * 2;
    unsigned short* t1_bf  = (unsigned short*)base;   base += (size_t)MPAD * DIM * 2;
    unsigned short* qkv_bf = (unsigned short*)base;   base += (size_t)MPAD * 3 * DIM * 2;
    unsigned short* hid_bf = (unsigned short*)base;   base += (size_t)MPAD * MLP * 2;
    unsigned short* xp_bf  = (unsigned short*)base;   base += (size_t)BB * NP * PD * 2;
    unsigned short* wt_bf  = (unsigned short*)base;   base += (size_t)MLP * DIM * 2;
    float* pe_f32 = (float*)hid_bf;   // patch-embed fp32 out, alias (consumed pre-loop)

    const int threads = 256;
    const int mblk = (BS + 127) / 128;   // 37

    patchify_k<<<(BB * NP * PD + 255) / 256, threads, 0, stream>>>(img, xp_bf);
    convT_k<<<dim3(DIM / 32, PD / 32), threads, 0, stream>>>(patch_w, wt_bf, PD, DIM);
    mgemm_k<3><<<dim3(DIM / 128, (BB * NP) / 128), threads, 0, stream>>>(
        xp_bf, wt_bf, patch_b, pe_f32, BB * NP, DIM, PD);
    build_x_k<<<(BB * SS * DIM + 255) / 256, threads, 0, stream>>>(pe_f32, cls, pos, x);

    for (int l = 0; l < DEPTH; ++l) {
        ln_k<<<BS, threads, 0, stream>>>(x, ln1_g + l * DIM, ln1_b + l * DIM, y_bf);
        convT_k<<<dim3(3 * DIM / 32, DIM / 32), threads, 0, stream>>>(
            qkv_w + (size_t)l * DIM * 3 * DIM, wt_bf, DIM, 3 * DIM);
        mgemm_k<0><<<dim3(3 * DIM / 128, mblk), threads, 0, stream>>>(
            y_bf, wt_bf, nullptr, qkv_bf, BS, 3 * DIM, DIM);
        // MFMA flash attention -> t1
        mattn_k<<<dim3(BB * HEADS, NKT), threads, 0, stream>>>(qkv_bf, t1_bf);
        convT_k<<<dim3(DIM / 32, DIM / 32), threads, 0, stream>>>(
            out_w + (size_t)l * DIM * DIM, wt_bf, DIM, DIM);
        mgemm_k<2><<<dim3(DIM / 128, mblk), threads, 0, stream>>>(
            t1_bf, wt_bf, out_b + l * DIM, x, BS, DIM, DIM);
        ln_k<<<BS, threads, 0, stream>>>(x, ln2_g + l * DIM, ln2_b + l * DIM, y_bf);
        convT_k<<<dim3(MLP / 32, DIM / 32), threads, 0, stream>>>(
            ff1_w + (size_t)l * DIM * MLP, wt_bf, DIM, MLP);
        mgemm_k<1><<<dim3(MLP / 128, mblk), threads, 0, stream>>>(
            y_bf, wt_bf, ff1_b + l * MLP, hid_bf, BS, MLP, DIM);
        convT_k<<<dim3(DIM / 32, MLP / 32), threads, 0, stream>>>(
            ff2_w + (size_t)l * MLP * DIM, wt_bf, MLP, DIM);
        mgemm_k<2><<<dim3(DIM / 128, mblk), threads, 0, stream>>>(
            hid_bf, wt_bf, ff2_b + l * DIM, x, BS, DIM, MLP);
    }

    copy_out_k<<<(BB * NP * DIM + 255) / 256, threads, 0, stream>>>(x, out);
}

// Round 5
// 2410.118 us; speedup vs baseline: 10.6413x; 1.0832x over previous
//
#include <hip/hip_runtime.h>
#include <hip/hip_bf16.h>
#include <math.h>

// Problem constants (ViT): B=8, C=3, H=384, P=16 -> 24x24=576 patches, S=577
#define BB 8
#define CC 3
#define HH 384
#define PP 16
#define HP 24            // H/P
#define NP 576           // patches per image
#define PD 768           // patch dim = C*P*P
#define DIM 768
#define DEPTH 8
#define HEADS 12
#define DH 64            // DIM/HEADS
#define MLP 3072
#define SS 577           // seq len = NP+1
#define BS (BB*SS)       // 4616 rows
#define MPAD 4736        // 37*128, padded row count for GEMM A-operands
#define LN_EPS 1e-5f
#define NKT 10           // ceil(577/64) key tiles
#define QW (3*DIM)       // qkv row width 2304

typedef __attribute__((ext_vector_type(8))) short s8v;   // 8 bf16 = 4 VGPRs
typedef __attribute__((ext_vector_type(4))) float f4v;   // MFMA accum

__device__ __forceinline__ float bf2f(unsigned short s) {
    union { unsigned u; float f; } x;
    x.u = ((unsigned)s) << 16;
    return x.f;
}
__device__ __forceinline__ unsigned short f2bfu(float f) {
    __hip_bfloat16 h = __float2bfloat16(f);
    return *reinterpret_cast<unsigned short*>(&h);
}

// async global->LDS, 16B per lane; LDS dest = base + lane*16 (wave-uniform base)
__device__ __forceinline__ void async16(void* lds, const void* g) {
    __builtin_amdgcn_global_load_lds(
        (const __attribute__((address_space(1))) void*)(uintptr_t)g,
        (__attribute__((address_space(3))) void*)(unsigned)(uintptr_t)lds,
        16, 0, 0);
}

// ---------------------------------------------------------------------------
// Patchify: img (B,C,H,H) -> Xp_bf (B*NP, PD) bf16, vec index (p1*P+p2)*C + c
// ---------------------------------------------------------------------------
__global__ __launch_bounds__(256) void patchify_k(const float* __restrict__ img,
                                                  unsigned short* __restrict__ xp) {
    int idx = blockIdx.x * 256 + threadIdx.x;
    const int total = BB * NP * PD;
    if (idx >= total) return;
    int b = idx / (NP * PD);
    int r = idx % (NP * PD);
    int n = r / PD;
    int j = r % PD;
    int c  = j % CC;
    int t  = j / CC;
    int p2 = t % PP;
    int p1 = t / PP;
    int hh = n / HP;
    int ww = n % HP;
    int row = hh * PP + p1;
    int col = ww * PP + p2;
    xp[idx] = f2bfu(img[(((size_t)b * CC + c) * HH + row) * HH + col]);
}

// ---------------------------------------------------------------------------
// Weight convert + transpose: W (K,N) fp32 -> Wt (N,K) bf16.  K,N % 32 == 0.
// ---------------------------------------------------------------------------
__global__ __launch_bounds__(256) void convT_k(const float* __restrict__ W,
                                               unsigned short* __restrict__ Wt,
                                               int K, int N) {
    __shared__ float t[32][33];
    int tx = threadIdx.x & 31, ty = threadIdx.x >> 5;   // 32 x 8
    int n0 = blockIdx.x * 32, k0 = blockIdx.y * 32;
#pragma unroll
    for (int i = 0; i < 32; i += 8)
        t[ty + i][tx] = W[(size_t)(k0 + ty + i) * N + n0 + tx];
    __syncthreads();
#pragma unroll
    for (int i = 0; i < 32; i += 8)
        Wt[(size_t)(n0 + ty + i) * K + k0 + tx] = f2bfu(t[tx][ty + i]);
}

// ---------------------------------------------------------------------------
// Build residual stream x (B,S,DIM) fp32
// ---------------------------------------------------------------------------
__global__ __launch_bounds__(256) void build_x_k(const float* __restrict__ pe,
                                                 const float* __restrict__ cls,
                                                 const float* __restrict__ pos,
                                                 float* __restrict__ x) {
    int idx = blockIdx.x * 256 + threadIdx.x;
    const int total = BB * SS * DIM;
    if (idx >= total) return;
    int b = idx / (SS * DIM);
    int r = idx % (SS * DIM);
    int i = r / DIM;
    int d = r % DIM;
    float p = pos[i * DIM + d];
    float v = (i == 0) ? cls[d] : pe[((size_t)b * NP + (i - 1)) * DIM + d];
    x[idx] = v + p;
}

// ---------------------------------------------------------------------------
// LayerNorm: x fp32 -> y bf16. One block per row.
// ---------------------------------------------------------------------------
__global__ __launch_bounds__(256) void ln_k(const float* __restrict__ x,
                                            const float* __restrict__ g,
                                            const float* __restrict__ bt,
                                            unsigned short* __restrict__ y) {
    __shared__ float sm[8];
    int row = blockIdx.x, tid = threadIdx.x;
    const float* xr = x + (size_t)row * DIM;
    float v0 = xr[tid], v1 = xr[tid + 256], v2 = xr[tid + 512];
    float s = v0 + v1 + v2;
    for (int o = 32; o; o >>= 1) s += __shfl_xor(s, o);
    if ((tid & 63) == 0) sm[tid >> 6] = s;
    __syncthreads();
    float mean = (sm[0] + sm[1] + sm[2] + sm[3]) * (1.f / 768.f);
    float q0 = v0 - mean, q1 = v1 - mean, q2 = v2 - mean;
    float s2 = q0 * q0 + q1 * q1 + q2 * q2;
    for (int o = 32; o; o >>= 1) s2 += __shfl_xor(s2, o);
    if ((tid & 63) == 0) sm[4 + (tid >> 6)] = s2;
    __syncthreads();
    float var = (sm[4] + sm[5] + sm[6] + sm[7]) * (1.f / 768.f);
    float rstd = rsqrtf(var + LN_EPS);
    unsigned short* yr = y + (size_t)row * DIM;
    yr[tid]       = f2bfu(q0 * rstd * g[tid]       + bt[tid]);
    yr[tid + 256] = f2bfu(q1 * rstd * g[tid + 256] + bt[tid + 256]);
    yr[tid + 512] = f2bfu(q2 * rstd * g[tid + 512] + bt[tid + 512]);
}

// ---------------------------------------------------------------------------
// bf16 MFMA GEMM v2: double-buffered one-barrier K-loop + optional split-K.
//   A:  (Mpad, K) bf16 row-major; Bt: (N, K) bf16 row-major
//   OP 0: bf16 out = acc + bias      (bias may be null)
//   OP 1: bf16 out = gelu(acc+bias)
//   OP 2: fp32 C += acc + bias       (residual; atomicAdd when SPLIT>1,
//                                     bias added only by slice z==0)
//   OP 3: fp32 out = acc + bias
// 128x128 tile, 256 thr (4 waves, 2x2), 16x16x32 MFMA, BK=32.
// Pipeline: stage(t+1) -> MFMA(t) -> barrier (vmcnt drain overlaps compute).
// ---------------------------------------------------------------------------
template <int OP, int SPLIT>
__global__ __launch_bounds__(256) void mgemm_k(const unsigned short* __restrict__ A,
                                               const unsigned short* __restrict__ Bt,
                                               const float* __restrict__ bias,
                                               void* __restrict__ Cv,
                                               int M, int N, int K) {
    __shared__ unsigned short Al[2][128 * 32];
    __shared__ unsigned short Bl[2][128 * 32];
    int tid = threadIdx.x;
    int wv = tid >> 6, lane = tid & 63;
    int quad = lane >> 4, l16 = lane & 15;
    int m0 = blockIdx.y * 128, n0 = blockIdx.x * 128;
    int wm = (wv >> 1) * 64, wn = (wv & 1) * 64;
    int rg = lane >> 2;            // row within 16-row staging group
    int kc = (lane & 3) * 8;       // k element offset (8 bf16 = 16B)

    const int Ks = K / SPLIT;
    const int kbase = blockIdx.z * Ks;
    const int T = Ks / 32;

    f4v acc[4][4];
    const f4v zero = {0.f, 0.f, 0.f, 0.f};
#pragma unroll
    for (int i = 0; i < 4; ++i)
#pragma unroll
        for (int j = 0; j < 4; ++j) acc[i][j] = zero;

    auto stage = [&](int t, int bufi) {
#pragma unroll
        for (int gg = 0; gg < 2; ++gg) {
            int g = wv + gg * 4;                // staging group 0..7
            const unsigned short* ga =
                A + (size_t)(m0 + g * 16 + rg) * K + kbase + t * 32 + kc;
            async16(&Al[bufi][g * 512], ga);
            const unsigned short* gb =
                Bt + (size_t)(n0 + g * 16 + rg) * K + kbase + t * 32 + kc;
            async16(&Bl[bufi][g * 512], gb);
        }
    };

    stage(0, 0);
    __syncthreads();

    for (int t = 0; t < T; ++t) {
        int cur = t & 1;
        if (t + 1 < T) stage(t + 1, cur ^ 1);   // loads overlap MFMAs below

        s8v af[4], bfr[4];
#pragma unroll
        for (int i = 0; i < 4; ++i)
            af[i] = *reinterpret_cast<const s8v*>(&Al[cur][(wm + i * 16 + l16) * 32 + quad * 8]);
#pragma unroll
        for (int j = 0; j < 4; ++j)
            bfr[j] = *reinterpret_cast<const s8v*>(&Bl[cur][(wn + j * 16 + l16) * 32 + quad * 8]);
#pragma unroll
        for (int i = 0; i < 4; ++i)
#pragma unroll
            for (int j = 0; j < 4; ++j)
                acc[i][j] = __builtin_amdgcn_mfma_f32_16x16x32_bf16(af[i], bfr[j], acc[i][j], 0, 0, 0);

        if (t + 1 < T) __syncthreads();         // drains vmcnt for next buffer
    }

    // epilogue: C/D layout col=lane&15, row=quad*4+reg
#pragma unroll
    for (int j = 0; j < 4; ++j) {
        int col = n0 + wn + j * 16 + l16;
        float bj = bias ? bias[col] : 0.f;
        if (SPLIT > 1 && blockIdx.z != 0) bj = 0.f;
#pragma unroll
        for (int i = 0; i < 4; ++i) {
#pragma unroll
            for (int r = 0; r < 4; ++r) {
                int row = m0 + wm + i * 16 + quad * 4 + r;
                if (row >= M) continue;
                float v = acc[i][j][r] + bj;
                size_t idx = (size_t)row * N + col;
                if (OP == 0) {
                    ((unsigned short*)Cv)[idx] = f2bfu(v);
                } else if (OP == 1) {
                    v = 0.5f * v * (1.f + erff(v * 0.70710678118654752f));
                    ((unsigned short*)Cv)[idx] = f2bfu(v);
                } else if (OP == 2) {
                    float* C = (float*)Cv;
                    if (SPLIT > 1) atomicAdd(&C[idx], v);
                    else C[idx] += v;
                } else {
                    ((float*)Cv)[idx] = v;
                }
            }
        }
    }
}

// ---------------------------------------------------------------------------
// MFMA flash attention (bf16, fp32 softmax). One block per (b*h, q-tile 64).
// 4 waves; wave w owns queries q0+w*16..+15. No 1/sqrt(d) scale (faithful).
// ---------------------------------------------------------------------------
__global__ __launch_bounds__(256) void mattn_k(const unsigned short* __restrict__ qkv,
                                               unsigned short* __restrict__ o) {
    __shared__ unsigned short Kl[64 * 72];
    __shared__ unsigned short Vt[64 * 72];
    __shared__ unsigned short Pw[4][16 * 72];

    int tid = threadIdx.x;
    int w = tid >> 6, lane = tid & 63, quad = lane >> 4, l16 = lane & 15;
    int bh = blockIdx.x;
    int b = bh / HEADS, h = bh % HEADS;
    int q0 = blockIdx.y * 64;

    int qq = q0 + w * 16 + l16;
    if (qq > SS - 1) qq = SS - 1;
    const unsigned short* qp = qkv + (size_t)(b * SS + qq) * QW + h * DH + quad * 8;
    s8v aq0 = *reinterpret_cast<const s8v*>(qp);
    s8v aq1 = *reinterpret_cast<const s8v*>(qp + 32);

    float m[4], l[4];
    f4v O[4];
    const f4v zero = {0.f, 0.f, 0.f, 0.f};
#pragma unroll
    for (int r = 0; r < 4; ++r) { m[r] = -INFINITY; l[r] = 0.f; }
#pragma unroll
    for (int dg = 0; dg < 4; ++dg) O[dg] = zero;

    for (int t = 0; t < NKT; ++t) {
        int k0 = t * 64;
        __syncthreads();
#pragma unroll
        for (int rr = 0; rr < 2; ++rr) {
            int cid = tid + rr * 256;
            int row = cid >> 3, cb = (cid & 7) * 8;
            s8v kv = *reinterpret_cast<const s8v*>(
                qkv + (size_t)(b * SS + k0 + row) * QW + DIM + h * DH + cb);
            *reinterpret_cast<s8v*>(&Kl[row * 72 + cb]) = kv;
        }
        {
            int kb = (tid & 15) * 4, db = (tid >> 4) * 4;
            const unsigned short* vb = qkv + (size_t)(b * SS + k0 + kb) * QW + 2 * DIM + h * DH + db;
            ushort4 r0 = *reinterpret_cast<const ushort4*>(vb);
            ushort4 r1 = *reinterpret_cast<const ushort4*>(vb + QW);
            ushort4 r2 = *reinterpret_cast<const ushort4*>(vb + 2 * QW);
            ushort4 r3 = *reinterpret_cast<const ushort4*>(vb + 3 * QW);
            ushort4 w0 = {r0.x, r1.x, r2.x, r3.x};
            ushort4 w1 = {r0.y, r1.y, r2.y, r3.y};
            ushort4 w2 = {r0.z, r1.z, r2.z, r3.z};
            ushort4 w3 = {r0.w, r1.w, r2.w, r3.w};
            *reinterpret_cast<ushort4*>(&Vt[(db + 0) * 72 + kb]) = w0;
            *reinterpret_cast<ushort4*>(&Vt[(db + 1) * 72 + kb]) = w1;
            *reinterpret_cast<ushort4*>(&Vt[(db + 2) * 72 + kb]) = w2;
            *reinterpret_cast<ushort4*>(&Vt[(db + 3) * 72 + kb]) = w3;
        }
        __syncthreads();

        f4v s[4];
#pragma unroll
        for (int kk = 0; kk < 4; ++kk) {
            const unsigned short* kp = &Kl[(kk * 16 + l16) * 72 + quad * 8];
            s8v b0 = *reinterpret_cast<const s8v*>(kp);
            s8v b1 = *reinterpret_cast<const s8v*>(kp + 32);
            f4v z = zero;
            z = __builtin_amdgcn_mfma_f32_16x16x32_bf16(aq0, b0, z, 0, 0, 0);
            z = __builtin_amdgcn_mfma_f32_16x16x32_bf16(aq1, b1, z, 0, 0, 0);
            s[kk] = z;
        }
        int kvalid = SS - k0;
        if (kvalid < 64) {
#pragma unroll
            for (int kk = 0; kk < 4; ++kk)
                if (kk * 16 + l16 >= kvalid) {
                    f4v mk = {-1e30f, -1e30f, -1e30f, -1e30f};
                    s[kk] = mk;
                }
        }
        float alpha[4];
#pragma unroll
        for (int r = 0; r < 4; ++r) {
            float mx = fmaxf(fmaxf(s[0][r], s[1][r]), fmaxf(s[2][r], s[3][r]));
#pragma unroll
            for (int off = 1; off < 16; off <<= 1) mx = fmaxf(mx, __shfl_xor(mx, off));
            float mn = fmaxf(m[r], mx);
            alpha[r] = __expf(m[r] - mn);
            m[r] = mn;
            float ps = 0.f;
#pragma unroll
            for (int kk = 0; kk < 4; ++kk) {
                float p = __expf(s[kk][r] - mn);
                ps += p;
                Pw[w][(quad * 4 + r) * 72 + kk * 16 + l16] = f2bfu(p);
            }
#pragma unroll
            for (int off = 1; off < 16; off <<= 1) ps += __shfl_xor(ps, off);
            l[r] = l[r] * alpha[r] + ps;
        }
#pragma unroll
        for (int dg = 0; dg < 4; ++dg)
#pragma unroll
            for (int r = 0; r < 4; ++r) O[dg][r] *= alpha[r];

        s8v ap0 = *reinterpret_cast<const s8v*>(&Pw[w][l16 * 72 + quad * 8]);
        s8v ap1 = *reinterpret_cast<const s8v*>(&Pw[w][l16 * 72 + 32 + quad * 8]);
#pragma unroll
        for (int dg = 0; dg < 4; ++dg) {
            const unsigned short* vp = &Vt[(dg * 16 + l16) * 72 + quad * 8];
            s8v bv0 = *reinterpret_cast<const s8v*>(vp);
            s8v bv1 = *reinterpret_cast<const s8v*>(vp + 32);
            O[dg] = __builtin_amdgcn_mfma_f32_16x16x32_bf16(ap0, bv0, O[dg], 0, 0, 0);
            O[dg] = __builtin_amdgcn_mfma_f32_16x16x32_bf16(ap1, bv1, O[dg], 0, 0, 0);
        }
    }

#pragma unroll
    for (int r = 0; r < 4; ++r) {
        int q = q0 + w * 16 + quad * 4 + r;
        if (q >= SS) continue;
        float inv = 1.f / l[r];
        unsigned short* op = o + (size_t)(b * SS + q) * DIM + h * DH + l16;
#pragma unroll
        for (int dg = 0; dg < 4; ++dg)
            op[dg * 16] = f2bfu(O[dg][r] * inv);
    }
}

// ---------------------------------------------------------------------------
// Output: x[:, 1:, :] fp32 -> out (B, NP, DIM)
// ---------------------------------------------------------------------------
__global__ __launch_bounds__(256) void copy_out_k(const float* __restrict__ x,
                                                  float* __restrict__ out) {
    int idx = blockIdx.x * 256 + threadIdx.x;
    const int total = BB * NP * DIM;
    if (idx >= total) return;
    int b = idx / (NP * DIM);
    int r = idx % (NP * DIM);
    int n = r / DIM;
    int d = r % DIM;
    out[idx] = x[((size_t)b * SS + 1 + n) * DIM + d];
}

// ---------------------------------------------------------------------------
extern "C" void kernel_launch(void* const* d_in, const int* in_sizes, int n_in,
                              void* d_out, int out_size, void* d_ws, size_t ws_size,
                              hipStream_t stream) {
    const float* img     = (const float*)d_in[0];
    const float* pos     = (const float*)d_in[1];
    const float* cls     = (const float*)d_in[2];
    const float* patch_w = (const float*)d_in[3];
    const float* patch_b = (const float*)d_in[4];
    const float* ln1_g   = (const float*)d_in[5];
    const float* ln1_b   = (const float*)d_in[6];
    const float* qkv_w   = (const float*)d_in[7];
    const float* out_w   = (const float*)d_in[8];
    const float* out_b   = (const float*)d_in[9];
    const float* ln2_g   = (const float*)d_in[10];
    const float* ln2_b   = (const float*)d_in[11];
    const float* ff1_w   = (const float*)d_in[12];
    const float* ff1_b   = (const float*)d_in[13];
    const float* ff2_w   = (const float*)d_in[14];
    const float* ff2_b   = (const float*)d_in[15];
    float* out = (float*)d_out;

    // workspace layout
    char* base = (char*)d_ws;
    float* x = (float*)base;                          base += (size_t)BS * DIM * 4;
    unsigned short* y_bf   = (unsigned short*)base;   base += (size_t)MPAD * DIM * 2;
    unsigned short* t1_bf  = (unsigned short*)base;   base += (size_t)MPAD * DIM * 2;
    unsigned short* qkv_bf = (unsigned short*)base;   base += (size_t)MPAD * 3 * DIM * 2;
    unsigned short* hid_bf = (unsigned short*)base;   base += (size_t)MPAD * MLP * 2;
    unsigned short* xp_bf  = (unsigned short*)base;   base += (size_t)BB * NP * PD * 2;
    unsigned short* wt_bf  = (unsigned short*)base;   base += (size_t)MLP * DIM * 2;
    float* pe_f32 = (float*)hid_bf;   // patch-embed fp32 out, alias (consumed pre-loop)

    const int threads = 256;
    const int mblk = (BS + 127) / 128;   // 37

    patchify_k<<<(BB * NP * PD + 255) / 256, threads, 0, stream>>>(img, xp_bf);
    convT_k<<<dim3(DIM / 32, PD / 32), threads, 0, stream>>>(patch_w, wt_bf, PD, DIM);
    mgemm_k<3, 1><<<dim3(DIM / 128, (BB * NP) / 128), threads, 0, stream>>>(
        xp_bf, wt_bf, patch_b, pe_f32, BB * NP, DIM, PD);
    build_x_k<<<(BB * SS * DIM + 255) / 256, threads, 0, stream>>>(pe_f32, cls, pos, x);

    for (int l = 0; l < DEPTH; ++l) {
        ln_k<<<BS, threads, 0, stream>>>(x, ln1_g + l * DIM, ln1_b + l * DIM, y_bf);
        convT_k<<<dim3(3 * DIM / 32, DIM / 32), threads, 0, stream>>>(
            qkv_w + (size_t)l * DIM * 3 * DIM, wt_bf, DIM, 3 * DIM);
        mgemm_k<0, 1><<<dim3(3 * DIM / 128, mblk), threads, 0, stream>>>(
            y_bf, wt_bf, nullptr, qkv_bf, BS, 3 * DIM, DIM);
        // MFMA flash attention -> t1
        mattn_k<<<dim3(BB * HEADS, NKT), threads, 0, stream>>>(qkv_bf, t1_bf);
        // x += t1 @ out_w + out_b   (split-K x2, atomic fp32 accumulate)
        convT_k<<<dim3(DIM / 32, DIM / 32), threads, 0, stream>>>(
            out_w + (size_t)l * DIM * DIM, wt_bf, DIM, DIM);
        mgemm_k<2, 2><<<dim3(DIM / 128, mblk, 2), threads, 0, stream>>>(
            t1_bf, wt_bf, out_b + l * DIM, x, BS, DIM, DIM);
        ln_k<<<BS, threads, 0, stream>>>(x, ln2_g + l * DIM, ln2_b + l * DIM, y_bf);
        convT_k<<<dim3(MLP / 32, DIM / 32), threads, 0, stream>>>(
            ff1_w + (size_t)l * DIM * MLP, wt_bf, DIM, MLP);
        mgemm_k<1, 1><<<dim3(MLP / 128, mblk), threads, 0, stream>>>(
            y_bf, wt_bf, ff1_b + l * MLP, hid_bf, BS, MLP, DIM);
        // x += hid @ w2 + b2   (split-K x4, atomic fp32 accumulate)
        convT_k<<<dim3(DIM / 32, MLP / 32), threads, 0, stream>>>(
            ff2_w + (size_t)l * MLP * DIM, wt_bf, MLP, DIM);
        mgemm_k<2, 4><<<dim3(DIM / 128, mblk, 4), threads, 0, stream>>>(
            hid_bf, wt_bf, ff2_b + l * DIM, x, BS, DIM, MLP);
    }

    copy_out_k<<<(BB * NP * DIM + 255) / 256, threads, 0, stream>>>(x, out);
}